// Round 6
// baseline (1261.322 us; speedup 1.0000x reference)
//
#include <hip/hip_runtime.h>
#include <hip/hip_bf16.h>

#define N_NODES 100000
#define N_EDGES 1280000
#define D 64
#define NB ((N_NODES + 255) / 256)   // 391 scan blocks

// ==================== CSR build ====================

// 4 edges per thread via int4 (N_EDGES % 4 == 0).
__global__ void hist_kernel(const int4* __restrict__ row4, int* __restrict__ deg) {
    int t = blockIdx.x * blockDim.x + threadIdx.x;
    if (t < N_EDGES / 4) {
        int4 r = row4[t];
        atomicAdd(&deg[r.x], 1);
        atomicAdd(&deg[r.y], 1);
        atomicAdd(&deg[r.z], 1);
        atomicAdd(&deg[r.w], 1);
    }
}

// Per-block exclusive scan of deg -> cursor, raw block totals -> bsum.
__global__ void scan_block_kernel(const int* __restrict__ deg,
                                  int* __restrict__ cursor,
                                  int* __restrict__ bsum) {
    __shared__ int s[256];
    int tid = threadIdx.x;
    int gid = blockIdx.x * 256 + tid;
    int v = (gid < N_NODES) ? deg[gid] : 0;
    s[tid] = v;
    __syncthreads();
    for (int d = 1; d < 256; d <<= 1) {
        int t = (tid >= d) ? s[tid - d] : 0;
        __syncthreads();
        s[tid] += t;
        __syncthreads();
    }
    if (gid < N_NODES) cursor[gid] = s[tid] - v;       // block-local exclusive
    if (tid == 255) bsum[blockIdx.x] = s[255];
}

// Fused: block b reduces sum(bsum_raw[0..b)) itself, then adds to cursor.
__global__ void add_offsets_kernel(int* __restrict__ cursor,
                                   const int* __restrict__ bsum_raw) {
    __shared__ int red[256];
    int tid = threadIdx.x;
    int b = blockIdx.x;
    int sum = 0;
    for (int i = tid; i < b; i += 256) sum += bsum_raw[i];
    red[tid] = sum;
    __syncthreads();
    for (int off = 128; off > 0; off >>= 1) {
        if (tid < off) red[tid] += red[tid + off];
        __syncthreads();
    }
    int gid = b * 256 + tid;
    if (gid < N_NODES) cursor[gid] += red[0];
}

// Scatter edges into CSR order; 4 edges per thread. After this,
// cursor[r] == END offset of node r (start = cursor[r] - deg[r]).
__global__ void scatter_build_kernel(const int4* __restrict__ row4,
                                     const int4* __restrict__ col4,
                                     int* __restrict__ cursor,
                                     int* __restrict__ col_sorted) {
    int t = blockIdx.x * blockDim.x + threadIdx.x;
    if (t < N_EDGES / 4) {
        int4 r = row4[t];
        int4 c = col4[t];
        col_sorted[atomicAdd(&cursor[r.x], 1)] = c.x;
        col_sorted[atomicAdd(&cursor[r.y], 1)] = c.y;
        col_sorted[atomicAdd(&cursor[r.z], 1)] = c.z;
        col_sorted[atomicAdd(&cursor[r.w], 1)] = c.w;
    }
}

// ==================== dense precompute: y = x@W (bf16), out = x@Wr + bias ====
// Associativity: mean(x[col])@W == mean((x@W)[col]). Compute y once, densely.
// 512 threads = 8 waves; 32 nodes/block; W,Wr,x-tile staged in LDS (40 KB ->
// 4 blocks/CU -> 32 waves/CU). Lane f computes y[r][f], z[r][f].
__launch_bounds__(512, 8)
__global__ void xw_kernel(const float* __restrict__ x,
                          const float* __restrict__ W,
                          const float* __restrict__ Wr,
                          const float* __restrict__ bias,
                          __hip_bfloat16* __restrict__ y,
                          float* __restrict__ out) {
    __shared__ float Ws[D * D];
    __shared__ float Wrs[D * D];
    __shared__ float x_s[32][D];

    int tid = threadIdx.x;
    for (int i = tid; i < D * D / 4; i += 512) {
        ((float4*)Ws)[i]  = ((const float4*)W)[i];
        ((float4*)Wrs)[i] = ((const float4*)Wr)[i];
    }
    int base = blockIdx.x * 32;   // N_NODES % 32 == 0
    for (int i = tid; i < 32 * D / 4; i += 512) {
        ((float4*)x_s)[i] = ((const float4*)&x[(size_t)base * D])[i];
    }
    __syncthreads();

    int wv = tid >> 6;
    int f = tid & 63;
    float bf = bias[f];

#pragma unroll 1
    for (int nn = 0; nn < 4; ++nn) {
        int lr = wv * 4 + nn;
        int r = base + lr;
        float yv = 0.0f, zv = bf;
        const float4* xv = (const float4*)x_s[lr];
#pragma unroll
        for (int k4 = 0; k4 < 16; ++k4) {
            float4 xx = xv[k4];   // uniform address -> LDS broadcast
            int k = k4 * 4;
            yv += xx.x * Ws[(k + 0) * D + f] + xx.y * Ws[(k + 1) * D + f]
                + xx.z * Ws[(k + 2) * D + f] + xx.w * Ws[(k + 3) * D + f];
            zv += xx.x * Wrs[(k + 0) * D + f] + xx.y * Wrs[(k + 1) * D + f]
                + xx.z * Wrs[(k + 2) * D + f] + xx.w * Wrs[(k + 3) * D + f];
        }
        y[(size_t)r * D + f] = __float2bfloat16(yv);   // RNE
        out[(size_t)r * D + f] = zv;
    }
}

// ==================== pure gather-mean-add ====================
// 256 threads = 4 waves; each wave 4 nodes (16/block, 6250 blocks). No LDS.
// Lane (s,q), s in [0,4), q in [0,16): lane loads bf16x4 (8B) of features
// [4q,4q+4) of neighbor j+s -> 4 neighbor rows (128B each) per wave-load.
// Two nodes' gather loops interleaved for MLP. Butterfly xor16/32 reduces s.
// Final: all 64 lanes RMW 4 output rows (1KB coalesced): out += mean(y).
__device__ __forceinline__ float bf2f(unsigned short u) {
    union { unsigned int i; float f; } v;
    v.i = ((unsigned int)u) << 16;
    return v.f;
}

__launch_bounds__(256, 8)
__global__ void gather_kernel(const __hip_bfloat16* __restrict__ y,
                              const int* __restrict__ cursor_end,
                              const int* __restrict__ deg,
                              const int* __restrict__ col_sorted,
                              float* __restrict__ out) {
    int wv = threadIdx.x >> 6;
    int lane = threadIdx.x & 63;
    int s = lane >> 4;
    int q = lane & 15;
    int node0 = (blockIdx.x * 4 + wv) * 4;   // 100000 = 6250*16

    int4 nv = *(const int4*)&deg[node0];        // degrees (16B aligned)
    int4 ev = *(const int4*)&cursor_end[node0]; // end offsets

    int st0 = ev.x - nv.x, st1 = ev.y - nv.y, st2 = ev.z - nv.z, st3 = ev.w - nv.w;

    int i0 = 0, i1 = 0, i2 = 0, i3 = 0;
    if (lane < nv.x) i0 = col_sorted[st0 + lane];
    if (lane < nv.y) i1 = col_sorted[st1 + lane];
    if (lane < nv.z) i2 = col_sorted[st2 + lane];
    if (lane < nv.w) i3 = col_sorted[st3 + lane];

    float4 a0 = make_float4(0.f, 0.f, 0.f, 0.f);
    float4 a1 = a0, a2 = a0, a3 = a0;

    const unsigned short* yu = (const unsigned short*)y;

    // pair (0,1)
    {
        int m = nv.x > nv.y ? nv.x : nv.y;
        for (int j = 0; j < m; j += 4) {
            int jj = j + s;
            int c0 = __shfl(i0, jj, 64);
            int c1 = __shfl(i1, jj, 64);
            if (jj < nv.x) {
                ushort4 v = *(const ushort4*)&yu[(size_t)c0 * D + q * 4];
                a0.x += bf2f(v.x); a0.y += bf2f(v.y); a0.z += bf2f(v.z); a0.w += bf2f(v.w);
            }
            if (jj < nv.y) {
                ushort4 v = *(const ushort4*)&yu[(size_t)c1 * D + q * 4];
                a1.x += bf2f(v.x); a1.y += bf2f(v.y); a1.z += bf2f(v.z); a1.w += bf2f(v.w);
            }
        }
    }
    // pair (2,3)
    {
        int m = nv.z > nv.w ? nv.z : nv.w;
        for (int j = 0; j < m; j += 4) {
            int jj = j + s;
            int c2 = __shfl(i2, jj, 64);
            int c3 = __shfl(i3, jj, 64);
            if (jj < nv.z) {
                ushort4 v = *(const ushort4*)&yu[(size_t)c2 * D + q * 4];
                a2.x += bf2f(v.x); a2.y += bf2f(v.y); a2.z += bf2f(v.z); a2.w += bf2f(v.w);
            }
            if (jj < nv.w) {
                ushort4 v = *(const ushort4*)&yu[(size_t)c3 * D + q * 4];
                a3.x += bf2f(v.x); a3.y += bf2f(v.y); a3.z += bf2f(v.z); a3.w += bf2f(v.w);
            }
        }
    }

    // butterfly across s (bits 4,5)
#define BFLY(a) \
    a.x += __shfl_xor(a.x, 16, 64); a.y += __shfl_xor(a.y, 16, 64); \
    a.z += __shfl_xor(a.z, 16, 64); a.w += __shfl_xor(a.w, 16, 64); \
    a.x += __shfl_xor(a.x, 32, 64); a.y += __shfl_xor(a.y, 32, 64); \
    a.z += __shfl_xor(a.z, 32, 64); a.w += __shfl_xor(a.w, 32, 64);
    BFLY(a0) BFLY(a1) BFLY(a2) BFLY(a3)
#undef BFLY

    float inv0 = 1.0f / (float)(nv.x > 1 ? nv.x : 1);
    float inv1 = 1.0f / (float)(nv.y > 1 ? nv.y : 1);
    float inv2 = 1.0f / (float)(nv.z > 1 ? nv.z : 1);
    float inv3 = 1.0f / (float)(nv.w > 1 ? nv.w : 1);

    // lane (s,q) finalizes node node0+s, feature quad q: 1KB coalesced RMW
    float4 rr = (s == 0) ? a0 : (s == 1) ? a1 : (s == 2) ? a2 : a3;
    float invs = (s == 0) ? inv0 : (s == 1) ? inv1 : (s == 2) ? inv2 : inv3;
    size_t off = (size_t)(node0 + s) * D + q * 4;
    float4 z = *(const float4*)&out[off];
    z.x += rr.x * invs; z.y += rr.y * invs; z.z += rr.z * invs; z.w += rr.w * invs;
    *(float4*)&out[off] = z;
}

// ==================== round-5 fused aggregate (mid-tier fallback) ============
__launch_bounds__(512, 8)
__global__ void aggregate_kernel(const float* __restrict__ x,
                                 const int* __restrict__ cursor_end,
                                 const int* __restrict__ deg,
                                 const int* __restrict__ col_sorted,
                                 const float* __restrict__ W,
                                 const float* __restrict__ Wr,
                                 const float* __restrict__ bias,
                                 float* __restrict__ out) {
    __shared__ float Ws[D * D];
    __shared__ float Wrs[D * D];
    __shared__ float agg_s[8][D];
    __shared__ float x_s[8][D];

    for (int i = threadIdx.x; i < D * D / 4; i += 512) {
        ((float4*)Ws)[i]  = ((const float4*)W)[i];
        ((float4*)Wrs)[i] = ((const float4*)Wr)[i];
    }
    __syncthreads();

    int wv = threadIdx.x >> 6;
    int lane = threadIdx.x & 63;
    int s = lane >> 4;
    int q = lane & 15;
    float bf = bias[lane];

    int node0 = (blockIdx.x * 8 + wv) * 4;

#pragma unroll 1
    for (int nn = 0; nn < 4; ++nn) {
        int r = node0 + nn;
        int n = deg[r];
        int start = cursor_end[r] - n;

        float4 acc = make_float4(0.f, 0.f, 0.f, 0.f);
        for (int base = 0; base < n; base += 64) {
            int m = n - base; if (m > 64) m = 64;
            int idx = 0;
            if (lane < m) idx = col_sorted[start + base + lane];
            for (int j = 0; j < m; j += 4) {
                int jj = j + s;
                int c = __shfl(idx, jj, 64);
                if (jj < m) {
                    float4 v = *(const float4*)&x[(size_t)c * D + q * 4];
                    acc.x += v.x; acc.y += v.y; acc.z += v.z; acc.w += v.w;
                }
            }
        }
        acc.x += __shfl_xor(acc.x, 16, 64);
        acc.y += __shfl_xor(acc.y, 16, 64);
        acc.z += __shfl_xor(acc.z, 16, 64);
        acc.w += __shfl_xor(acc.w, 16, 64);
        acc.x += __shfl_xor(acc.x, 32, 64);
        acc.y += __shfl_xor(acc.y, 32, 64);
        acc.z += __shfl_xor(acc.z, 32, 64);
        acc.w += __shfl_xor(acc.w, 32, 64);

        float inv = 1.0f / (float)(n > 1 ? n : 1);
        if (lane < 16) {
            float4 a = make_float4(acc.x * inv, acc.y * inv, acc.z * inv, acc.w * inv);
            *(float4*)&agg_s[wv][q * 4] = a;
            *(float4*)&x_s[wv][q * 4] = *(const float4*)&x[(size_t)r * D + q * 4];
        }
        __builtin_amdgcn_wave_barrier();

        int f = lane;
        float o = bf;
        const float4* av = (const float4*)agg_s[wv];
        const float4* xv = (const float4*)x_s[wv];
#pragma unroll
        for (int k4 = 0; k4 < 16; ++k4) {
            float4 a = av[k4];
            float4 xx = xv[k4];
            int k = k4 * 4;
            o += a.x * Ws[(k + 0) * D + f] + xx.x * Wrs[(k + 0) * D + f];
            o += a.y * Ws[(k + 1) * D + f] + xx.y * Wrs[(k + 1) * D + f];
            o += a.z * Ws[(k + 2) * D + f] + xx.z * Wrs[(k + 2) * D + f];
            o += a.w * Ws[(k + 3) * D + f] + xx.w * Wrs[(k + 3) * D + f];
        }
        out[(size_t)r * D + f] = o;
        __builtin_amdgcn_wave_barrier();
    }
}

// ==================== atomic fallback path (needs 400 KB ws) ====================

__global__ void zero_kernel(float* __restrict__ summed, float* __restrict__ cnt) {
    int stride = gridDim.x * blockDim.x;
    int i = blockIdx.x * blockDim.x + threadIdx.x;
    const int total = N_NODES * D;
    for (int idx = i; idx < total; idx += stride) summed[idx] = 0.0f;
    for (int idx = i; idx < N_NODES; idx += stride) cnt[idx] = 0.0f;
}

__global__ void scatter_atomic_kernel(const float* __restrict__ x,
                                      const int* __restrict__ row,
                                      const int* __restrict__ col,
                                      float* __restrict__ summed,
                                      float* __restrict__ cnt) {
    long long gid = (long long)blockIdx.x * blockDim.x + threadIdx.x;
    const long long total = (long long)N_EDGES * D;
    if (gid >= total) return;
    int e = (int)(gid >> 6);
    int f = (int)(gid & 63);
    int r = row[e];
    int c = col[e];
    atomicAdd(&summed[r * D + f], x[c * D + f]);
    if (f == 0) atomicAdd(&cnt[r], 1.0f);
}

__global__ void finish_kernel(const float* __restrict__ x,
                              const float* __restrict__ W,
                              const float* __restrict__ Wr,
                              const float* __restrict__ bias,
                              const float* __restrict__ cnt,
                              float* __restrict__ out) {
    __shared__ float agg_s[4][D];
    __shared__ float x_s[4][D];
    int lrow = threadIdx.x >> 6;
    int f = threadIdx.x & 63;
    int r = blockIdx.x * 4 + lrow;

    float c = cnt[r];
    float inv = 1.0f / fmaxf(c, 1.0f);
    agg_s[lrow][f] = out[r * D + f] * inv;
    x_s[lrow][f] = x[r * D + f];
    __syncthreads();

    float acc = bias[f];
#pragma unroll 8
    for (int k = 0; k < D; ++k) {
        acc += agg_s[lrow][k] * W[k * D + f];
        acc += x_s[lrow][k] * Wr[k * D + f];
    }
    out[r * D + f] = acc;
}

// ==================== launch ====================

extern "C" void kernel_launch(void* const* d_in, const int* in_sizes, int n_in,
                              void* d_out, int out_size, void* d_ws, size_t ws_size,
                              hipStream_t stream) {
    const float* x    = (const float*)d_in[0];
    const int*   ei   = (const int*)d_in[1];   // [2, E]: row = ei, col = ei + E
    const float* W    = (const float*)d_in[2];
    const float* Wr   = (const float*)d_in[3];
    const float* bias = (const float*)d_in[4];
    float* out = (float*)d_out;

    const int* row = ei;
    const int* col = ei + N_EDGES;

    // ws layout: deg(N) | cursor(N) | bsum(2048B) | col_sorted(E) | y_bf16(N*D)
    const size_t csr_bytes = (size_t)2 * N_NODES * 4 + 2048 + (size_t)N_EDGES * 4;
    const size_t need_y    = csr_bytes + (size_t)N_NODES * D * 2;

    if (ws_size >= csr_bytes) {
        char* ws = (char*)d_ws;
        int* deg        = (int*)(ws);
        int* cursor     = (int*)(ws + (size_t)1 * N_NODES * 4);
        int* bsum       = (int*)(ws + (size_t)2 * N_NODES * 4);
        int* col_sorted = (int*)(ws + (size_t)2 * N_NODES * 4 + 2048);
        __hip_bfloat16* y = (__hip_bfloat16*)(ws + csr_bytes);

        hipMemsetAsync(deg, 0, (size_t)N_NODES * 4, stream);
        hist_kernel<<<(N_EDGES / 4 + 255) / 256, 256, 0, stream>>>((const int4*)row, deg);
        scan_block_kernel<<<NB, 256, 0, stream>>>(deg, cursor, bsum);
        add_offsets_kernel<<<NB, 256, 0, stream>>>(cursor, bsum);
        scatter_build_kernel<<<(N_EDGES / 4 + 255) / 256, 256, 0, stream>>>(
            (const int4*)row, (const int4*)col, cursor, col_sorted);

        if (ws_size >= need_y) {
            xw_kernel<<<N_NODES / 32, 512, 0, stream>>>(x, W, Wr, bias, y, out);
            gather_kernel<<<N_NODES / 16, 256, 0, stream>>>(y, cursor, deg, col_sorted, out);
        } else {
            aggregate_kernel<<<N_NODES / 32, 512, 0, stream>>>(x, cursor, deg, col_sorted, W, Wr, bias, out);
        }
    } else {
        // atomic fallback (round-1 verified): out doubles as summed[]
        float* cnt = (float*)d_ws;   // N_NODES floats
        zero_kernel<<<4096, 256, 0, stream>>>(out, cnt);
        long long total = (long long)N_EDGES * D;
        int blocks = (int)((total + 255) / 256);
        scatter_atomic_kernel<<<blocks, 256, 0, stream>>>(x, row, col, out, cnt);
        finish_kernel<<<(N_NODES + 3) / 4, 256, 0, stream>>>(x, W, Wr, bias, cnt, out);
    }
}

// Round 7
// 354.947 us; speedup vs baseline: 3.5536x; 3.5536x over previous
//
#include <hip/hip_runtime.h>
#include <hip/hip_bf16.h>

#define N_NODES 100000
#define N_EDGES 1280000
#define D 64
#define NB ((N_NODES + 255) / 256)   // 391 scan blocks

// ==================== CSR build ====================

// 4 edges per thread via int4 (N_EDGES % 4 == 0).
__global__ void hist_kernel(const int4* __restrict__ row4, int* __restrict__ deg) {
    int t = blockIdx.x * blockDim.x + threadIdx.x;
    if (t < N_EDGES / 4) {
        int4 r = row4[t];
        atomicAdd(&deg[r.x], 1);
        atomicAdd(&deg[r.y], 1);
        atomicAdd(&deg[r.z], 1);
        atomicAdd(&deg[r.w], 1);
    }
}

// Per-block exclusive scan of deg -> cursor, raw block totals -> bsum.
__global__ void scan_block_kernel(const int* __restrict__ deg,
                                  int* __restrict__ cursor,
                                  int* __restrict__ bsum) {
    __shared__ int s[256];
    int tid = threadIdx.x;
    int gid = blockIdx.x * 256 + tid;
    int v = (gid < N_NODES) ? deg[gid] : 0;
    s[tid] = v;
    __syncthreads();
    for (int d = 1; d < 256; d <<= 1) {
        int t = (tid >= d) ? s[tid - d] : 0;
        __syncthreads();
        s[tid] += t;
        __syncthreads();
    }
    if (gid < N_NODES) cursor[gid] = s[tid] - v;       // block-local exclusive
    if (tid == 255) bsum[blockIdx.x] = s[255];
}

// Fused: block b reduces sum(bsum_raw[0..b)) itself, then adds to cursor.
__global__ void add_offsets_kernel(int* __restrict__ cursor,
                                   const int* __restrict__ bsum_raw) {
    __shared__ int red[256];
    int tid = threadIdx.x;
    int b = blockIdx.x;
    int sum = 0;
    for (int i = tid; i < b; i += 256) sum += bsum_raw[i];
    red[tid] = sum;
    __syncthreads();
    for (int off = 128; off > 0; off >>= 1) {
        if (tid < off) red[tid] += red[tid + off];
        __syncthreads();
    }
    int gid = b * 256 + tid;
    if (gid < N_NODES) cursor[gid] += red[0];
}

// Scatter edges into CSR order; 4 edges per thread. After this,
// cursor[r] == END offset of node r (start = cursor[r] - deg[r]).
__global__ void scatter_build_kernel(const int4* __restrict__ row4,
                                     const int4* __restrict__ col4,
                                     int* __restrict__ cursor,
                                     int* __restrict__ col_sorted) {
    int t = blockIdx.x * blockDim.x + threadIdx.x;
    if (t < N_EDGES / 4) {
        int4 r = row4[t];
        int4 c = col4[t];
        col_sorted[atomicAdd(&cursor[r.x], 1)] = c.x;
        col_sorted[atomicAdd(&cursor[r.y], 1)] = c.y;
        col_sorted[atomicAdd(&cursor[r.z], 1)] = c.z;
        col_sorted[atomicAdd(&cursor[r.w], 1)] = c.w;
    }
}

// ==================== dense precompute (finish_kernel shape) ====================
// y = x@W stored as bf16 (packed pair-wise into dword stores);
// out = x@Wr + bias (fp32).
// 256 threads = 4 waves; 4 nodes/block; 25000 blocks. LDS = 1KB (x rows only);
// W/Wr read directly from global (16KB each -> L1-resident after first use).
// This is the round-1/3 proven structure — no launch_bounds, no big LDS,
// no per-lane 2-byte stores (the three suspects in round 6's 42x blowup).
__global__ void precompute_kernel(const float* __restrict__ x,
                                  const float* __restrict__ W,
                                  const float* __restrict__ Wr,
                                  const float* __restrict__ bias,
                                  unsigned int* __restrict__ y_packed,
                                  float* __restrict__ out) {
    __shared__ float x_s[4][D];
    int lrow = threadIdx.x >> 6;
    int f = threadIdx.x & 63;
    int r = blockIdx.x * 4 + lrow;     // N_NODES % 4 == 0

    x_s[lrow][f] = x[(size_t)r * D + f];
    __syncthreads();

    float yv = 0.0f;
    float zv = bias[f];
#pragma unroll 8
    for (int k = 0; k < D; ++k) {
        float xx = x_s[lrow][k];              // uniform address -> LDS broadcast
        yv += xx * W[k * D + f];              // coalesced, L1-hit
        zv += xx * Wr[k * D + f];
    }

    // pack two adjacent lanes' bf16 into one dword; even lanes store 4B each
    float ynb = __shfl_xor(yv, 1, 64);
    if ((f & 1) == 0) {
        __hip_bfloat16 lo = __float2bfloat16(yv);
        __hip_bfloat16 hi = __float2bfloat16(ynb);
        unsigned int lo_u = *(const unsigned short*)&lo;
        unsigned int hi_u = *(const unsigned short*)&hi;
        y_packed[((size_t)r * D + f) >> 1] = lo_u | (hi_u << 16);
    }
    out[(size_t)r * D + f] = zv;
}

// ==================== pure gather-mean-add (unchanged from round 6) ==========
__device__ __forceinline__ float bf2f(unsigned short u) {
    union { unsigned int i; float f; } v;
    v.i = ((unsigned int)u) << 16;
    return v.f;
}

__launch_bounds__(256, 8)
__global__ void gather_kernel(const unsigned short* __restrict__ yu,
                              const int* __restrict__ cursor_end,
                              const int* __restrict__ deg,
                              const int* __restrict__ col_sorted,
                              float* __restrict__ out) {
    int wv = threadIdx.x >> 6;
    int lane = threadIdx.x & 63;
    int s = lane >> 4;
    int q = lane & 15;
    int node0 = (blockIdx.x * 4 + wv) * 4;   // 100000 = 6250*16

    int4 nv = *(const int4*)&deg[node0];        // degrees (16B aligned)
    int4 ev = *(const int4*)&cursor_end[node0]; // end offsets

    int st0 = ev.x - nv.x, st1 = ev.y - nv.y, st2 = ev.z - nv.z, st3 = ev.w - nv.w;

    int i0 = 0, i1 = 0, i2 = 0, i3 = 0;
    if (lane < nv.x) i0 = col_sorted[st0 + lane];
    if (lane < nv.y) i1 = col_sorted[st1 + lane];
    if (lane < nv.z) i2 = col_sorted[st2 + lane];
    if (lane < nv.w) i3 = col_sorted[st3 + lane];

    float4 a0 = make_float4(0.f, 0.f, 0.f, 0.f);
    float4 a1 = a0, a2 = a0, a3 = a0;

    // pair (0,1)
    {
        int m = nv.x > nv.y ? nv.x : nv.y;
        for (int j = 0; j < m; j += 4) {
            int jj = j + s;
            int c0 = __shfl(i0, jj, 64);
            int c1 = __shfl(i1, jj, 64);
            if (jj < nv.x) {
                ushort4 v = *(const ushort4*)&yu[(size_t)c0 * D + q * 4];
                a0.x += bf2f(v.x); a0.y += bf2f(v.y); a0.z += bf2f(v.z); a0.w += bf2f(v.w);
            }
            if (jj < nv.y) {
                ushort4 v = *(const ushort4*)&yu[(size_t)c1 * D + q * 4];
                a1.x += bf2f(v.x); a1.y += bf2f(v.y); a1.z += bf2f(v.z); a1.w += bf2f(v.w);
            }
        }
    }
    // pair (2,3)
    {
        int m = nv.z > nv.w ? nv.z : nv.w;
        for (int j = 0; j < m; j += 4) {
            int jj = j + s;
            int c2 = __shfl(i2, jj, 64);
            int c3 = __shfl(i3, jj, 64);
            if (jj < nv.z) {
                ushort4 v = *(const ushort4*)&yu[(size_t)c2 * D + q * 4];
                a2.x += bf2f(v.x); a2.y += bf2f(v.y); a2.z += bf2f(v.z); a2.w += bf2f(v.w);
            }
            if (jj < nv.w) {
                ushort4 v = *(const ushort4*)&yu[(size_t)c3 * D + q * 4];
                a3.x += bf2f(v.x); a3.y += bf2f(v.y); a3.z += bf2f(v.z); a3.w += bf2f(v.w);
            }
        }
    }

    // butterfly across s (bits 4,5)
#define BFLY(a) \
    a.x += __shfl_xor(a.x, 16, 64); a.y += __shfl_xor(a.y, 16, 64); \
    a.z += __shfl_xor(a.z, 16, 64); a.w += __shfl_xor(a.w, 16, 64); \
    a.x += __shfl_xor(a.x, 32, 64); a.y += __shfl_xor(a.y, 32, 64); \
    a.z += __shfl_xor(a.z, 32, 64); a.w += __shfl_xor(a.w, 32, 64);
    BFLY(a0) BFLY(a1) BFLY(a2) BFLY(a3)
#undef BFLY

    float inv0 = 1.0f / (float)(nv.x > 1 ? nv.x : 1);
    float inv1 = 1.0f / (float)(nv.y > 1 ? nv.y : 1);
    float inv2 = 1.0f / (float)(nv.z > 1 ? nv.z : 1);
    float inv3 = 1.0f / (float)(nv.w > 1 ? nv.w : 1);

    // lane (s,q) finalizes node node0+s, feature quad q: 1KB coalesced RMW
    float4 rr = (s == 0) ? a0 : (s == 1) ? a1 : (s == 2) ? a2 : a3;
    float invs = (s == 0) ? inv0 : (s == 1) ? inv1 : (s == 2) ? inv2 : inv3;
    size_t off = (size_t)(node0 + s) * D + q * 4;
    float4 z = *(const float4*)&out[off];
    z.x += rr.x * invs; z.y += rr.y * invs; z.z += rr.z * invs; z.w += rr.w * invs;
    *(float4*)&out[off] = z;
}

// ==================== round-5 fused aggregate (mid-tier fallback) ============
__launch_bounds__(512, 8)
__global__ void aggregate_kernel(const float* __restrict__ x,
                                 const int* __restrict__ cursor_end,
                                 const int* __restrict__ deg,
                                 const int* __restrict__ col_sorted,
                                 const float* __restrict__ W,
                                 const float* __restrict__ Wr,
                                 const float* __restrict__ bias,
                                 float* __restrict__ out) {
    __shared__ float Ws[D * D];
    __shared__ float Wrs[D * D];
    __shared__ float agg_s[8][D];
    __shared__ float x_s[8][D];

    for (int i = threadIdx.x; i < D * D / 4; i += 512) {
        ((float4*)Ws)[i]  = ((const float4*)W)[i];
        ((float4*)Wrs)[i] = ((const float4*)Wr)[i];
    }
    __syncthreads();

    int wv = threadIdx.x >> 6;
    int lane = threadIdx.x & 63;
    int s = lane >> 4;
    int q = lane & 15;
    float bf = bias[lane];

    int node0 = (blockIdx.x * 8 + wv) * 4;

#pragma unroll 1
    for (int nn = 0; nn < 4; ++nn) {
        int r = node0 + nn;
        int n = deg[r];
        int start = cursor_end[r] - n;

        float4 acc = make_float4(0.f, 0.f, 0.f, 0.f);
        for (int base = 0; base < n; base += 64) {
            int m = n - base; if (m > 64) m = 64;
            int idx = 0;
            if (lane < m) idx = col_sorted[start + base + lane];
            for (int j = 0; j < m; j += 4) {
                int jj = j + s;
                int c = __shfl(idx, jj, 64);
                if (jj < m) {
                    float4 v = *(const float4*)&x[(size_t)c * D + q * 4];
                    acc.x += v.x; acc.y += v.y; acc.z += v.z; acc.w += v.w;
                }
            }
        }
        acc.x += __shfl_xor(acc.x, 16, 64);
        acc.y += __shfl_xor(acc.y, 16, 64);
        acc.z += __shfl_xor(acc.z, 16, 64);
        acc.w += __shfl_xor(acc.w, 16, 64);
        acc.x += __shfl_xor(acc.x, 32, 64);
        acc.y += __shfl_xor(acc.y, 32, 64);
        acc.z += __shfl_xor(acc.z, 32, 64);
        acc.w += __shfl_xor(acc.w, 32, 64);

        float inv = 1.0f / (float)(n > 1 ? n : 1);
        if (lane < 16) {
            float4 a = make_float4(acc.x * inv, acc.y * inv, acc.z * inv, acc.w * inv);
            *(float4*)&agg_s[wv][q * 4] = a;
            *(float4*)&x_s[wv][q * 4] = *(const float4*)&x[(size_t)r * D + q * 4];
        }
        __builtin_amdgcn_wave_barrier();

        int f = lane;
        float o = bf;
        const float4* av = (const float4*)agg_s[wv];
        const float4* xv = (const float4*)x_s[wv];
#pragma unroll
        for (int k4 = 0; k4 < 16; ++k4) {
            float4 a = av[k4];
            float4 xx = xv[k4];
            int k = k4 * 4;
            o += a.x * Ws[(k + 0) * D + f] + xx.x * Wrs[(k + 0) * D + f];
            o += a.y * Ws[(k + 1) * D + f] + xx.y * Wrs[(k + 1) * D + f];
            o += a.z * Ws[(k + 2) * D + f] + xx.z * Wrs[(k + 2) * D + f];
            o += a.w * Ws[(k + 3) * D + f] + xx.w * Wrs[(k + 3) * D + f];
        }
        out[(size_t)r * D + f] = o;
        __builtin_amdgcn_wave_barrier();
    }
}

// ==================== atomic fallback path (needs 400 KB ws) ====================

__global__ void zero_kernel(float* __restrict__ summed, float* __restrict__ cnt) {
    int stride = gridDim.x * blockDim.x;
    int i = blockIdx.x * blockDim.x + threadIdx.x;
    const int total = N_NODES * D;
    for (int idx = i; idx < total; idx += stride) summed[idx] = 0.0f;
    for (int idx = i; idx < N_NODES; idx += stride) cnt[idx] = 0.0f;
}

__global__ void scatter_atomic_kernel(const float* __restrict__ x,
                                      const int* __restrict__ row,
                                      const int* __restrict__ col,
                                      float* __restrict__ summed,
                                      float* __restrict__ cnt) {
    long long gid = (long long)blockIdx.x * blockDim.x + threadIdx.x;
    const long long total = (long long)N_EDGES * D;
    if (gid >= total) return;
    int e = (int)(gid >> 6);
    int f = (int)(gid & 63);
    int r = row[e];
    int c = col[e];
    atomicAdd(&summed[r * D + f], x[c * D + f]);
    if (f == 0) atomicAdd(&cnt[r], 1.0f);
}

__global__ void finish_kernel(const float* __restrict__ x,
                              const float* __restrict__ W,
                              const float* __restrict__ Wr,
                              const float* __restrict__ bias,
                              const float* __restrict__ cnt,
                              float* __restrict__ out) {
    __shared__ float agg_s[4][D];
    __shared__ float x_s[4][D];
    int lrow = threadIdx.x >> 6;
    int f = threadIdx.x & 63;
    int r = blockIdx.x * 4 + lrow;

    float c = cnt[r];
    float inv = 1.0f / fmaxf(c, 1.0f);
    agg_s[lrow][f] = out[r * D + f] * inv;
    x_s[lrow][f] = x[r * D + f];
    __syncthreads();

    float acc = bias[f];
#pragma unroll 8
    for (int k = 0; k < D; ++k) {
        acc += agg_s[lrow][k] * W[k * D + f];
        acc += x_s[lrow][k] * Wr[k * D + f];
    }
    out[r * D + f] = acc;
}

// ==================== launch ====================

extern "C" void kernel_launch(void* const* d_in, const int* in_sizes, int n_in,
                              void* d_out, int out_size, void* d_ws, size_t ws_size,
                              hipStream_t stream) {
    const float* x    = (const float*)d_in[0];
    const int*   ei   = (const int*)d_in[1];   // [2, E]: row = ei, col = ei + E
    const float* W    = (const float*)d_in[2];
    const float* Wr   = (const float*)d_in[3];
    const float* bias = (const float*)d_in[4];
    float* out = (float*)d_out;

    const int* row = ei;
    const int* col = ei + N_EDGES;

    // ws layout: deg(N) | cursor(N) | bsum(2048B) | col_sorted(E) | y_bf16(N*D)
    const size_t csr_bytes = (size_t)2 * N_NODES * 4 + 2048 + (size_t)N_EDGES * 4;
    const size_t need_y    = csr_bytes + (size_t)N_NODES * D * 2;

    if (ws_size >= csr_bytes) {
        char* ws = (char*)d_ws;
        int* deg        = (int*)(ws);
        int* cursor     = (int*)(ws + (size_t)1 * N_NODES * 4);
        int* bsum       = (int*)(ws + (size_t)2 * N_NODES * 4);
        int* col_sorted = (int*)(ws + (size_t)2 * N_NODES * 4 + 2048);
        unsigned int* y_packed = (unsigned int*)(ws + csr_bytes);

        hipMemsetAsync(deg, 0, (size_t)N_NODES * 4, stream);
        hist_kernel<<<(N_EDGES / 4 + 255) / 256, 256, 0, stream>>>((const int4*)row, deg);
        scan_block_kernel<<<NB, 256, 0, stream>>>(deg, cursor, bsum);
        add_offsets_kernel<<<NB, 256, 0, stream>>>(cursor, bsum);
        scatter_build_kernel<<<(N_EDGES / 4 + 255) / 256, 256, 0, stream>>>(
            (const int4*)row, (const int4*)col, cursor, col_sorted);

        if (ws_size >= need_y) {
            precompute_kernel<<<N_NODES / 4, 256, 0, stream>>>(x, W, Wr, bias, y_packed, out);
            gather_kernel<<<N_NODES / 16, 256, 0, stream>>>(
                (const unsigned short*)y_packed, cursor, deg, col_sorted, out);
        } else {
            aggregate_kernel<<<N_NODES / 32, 512, 0, stream>>>(x, cursor, deg, col_sorted, W, Wr, bias, out);
        }
    } else {
        // atomic fallback (round-1 verified): out doubles as summed[]
        float* cnt = (float*)d_ws;   // N_NODES floats
        zero_kernel<<<4096, 256, 0, stream>>>(out, cnt);
        long long total = (long long)N_EDGES * D;
        int blocks = (int)((total + 255) / 256);
        scatter_atomic_kernel<<<blocks, 256, 0, stream>>>(x, row, col, out, cnt);
        finish_kernel<<<(N_NODES + 3) / 4, 256, 0, stream>>>(x, W, Wr, bias, cnt, out);
    }
}

// Round 8
// 307.429 us; speedup vs baseline: 4.1028x; 1.1546x over previous
//
#include <hip/hip_runtime.h>
#include <hip/hip_bf16.h>

#define N_NODES 100000
#define N_EDGES 1280000
#define D 64
#define NB ((N_NODES + 255) / 256)   // 391 scan blocks

// ==================== CSR build ====================

// 4 edges per thread via int4 (N_EDGES % 4 == 0).
__global__ void hist_kernel(const int4* __restrict__ row4, int* __restrict__ deg) {
    int t = blockIdx.x * blockDim.x + threadIdx.x;
    if (t < N_EDGES / 4) {
        int4 r = row4[t];
        atomicAdd(&deg[r.x], 1);
        atomicAdd(&deg[r.y], 1);
        atomicAdd(&deg[r.z], 1);
        atomicAdd(&deg[r.w], 1);
    }
}

// Per-block exclusive scan of deg -> cursor, raw block totals -> bsum.
__global__ void scan_block_kernel(const int* __restrict__ deg,
                                  int* __restrict__ cursor,
                                  int* __restrict__ bsum) {
    __shared__ int s[256];
    int tid = threadIdx.x;
    int gid = blockIdx.x * 256 + tid;
    int v = (gid < N_NODES) ? deg[gid] : 0;
    s[tid] = v;
    __syncthreads();
    for (int d = 1; d < 256; d <<= 1) {
        int t = (tid >= d) ? s[tid - d] : 0;
        __syncthreads();
        s[tid] += t;
        __syncthreads();
    }
    if (gid < N_NODES) cursor[gid] = s[tid] - v;       // block-local exclusive
    if (tid == 255) bsum[blockIdx.x] = s[255];
}

// Fused: block b reduces sum(bsum_raw[0..b)) itself, then adds to cursor.
__global__ void add_offsets_kernel(int* __restrict__ cursor,
                                   const int* __restrict__ bsum_raw) {
    __shared__ int red[256];
    int tid = threadIdx.x;
    int b = blockIdx.x;
    int sum = 0;
    for (int i = tid; i < b; i += 256) sum += bsum_raw[i];
    red[tid] = sum;
    __syncthreads();
    for (int off = 128; off > 0; off >>= 1) {
        if (tid < off) red[tid] += red[tid + off];
        __syncthreads();
    }
    int gid = b * 256 + tid;
    if (gid < N_NODES) cursor[gid] += red[0];
}

// Scatter edges into CSR order; 4 edges per thread. After this,
// cursor[r] == END offset of node r (start = cursor[r] - deg[r]).
__global__ void scatter_build_kernel(const int4* __restrict__ row4,
                                     const int4* __restrict__ col4,
                                     int* __restrict__ cursor,
                                     int* __restrict__ col_sorted) {
    int t = blockIdx.x * blockDim.x + threadIdx.x;
    if (t < N_EDGES / 4) {
        int4 r = row4[t];
        int4 c = col4[t];
        col_sorted[atomicAdd(&cursor[r.x], 1)] = c.x;
        col_sorted[atomicAdd(&cursor[r.y], 1)] = c.y;
        col_sorted[atomicAdd(&cursor[r.z], 1)] = c.z;
        col_sorted[atomicAdd(&cursor[r.w], 1)] = c.w;
    }
}

// ==================== dense precompute, register-blocked =====================
// y = x@W (bf16, pair-packed dword stores); out = x@Wr + bias (fp32).
// 256 threads = 4 waves; 8 nodes/wave -> 32 nodes/block; 3125 blocks.
// W/Wr staged in LDS (32 KB) + x tile (8 KB) = 40 KB -> 4 blocks/CU.
// Key fix vs round 7 (111 us, L1-BW-bound): each W/Wr column value is loaded
// ONCE per k and applied to 8 nodes (8x amortization). x quads arrive as
// wave-uniform ds_read_b128 broadcasts. No launch_bounds (round 6 spill
// lesson: forced wave/EU caps VGPRs and spills to scratch at 42x traffic).
__global__ void precompute_kernel(const float* __restrict__ x,
                                  const float* __restrict__ W,
                                  const float* __restrict__ Wr,
                                  const float* __restrict__ bias,
                                  unsigned int* __restrict__ y_packed,
                                  float* __restrict__ out) {
    __shared__ float Ws[D * D];
    __shared__ float Wrs[D * D];
    __shared__ float x_s[32][D];

    int tid = threadIdx.x;
    int base = blockIdx.x * 32;           // N_NODES % 32 == 0
    for (int i = tid; i < D * D / 4; i += 256) {
        ((float4*)Ws)[i]  = ((const float4*)W)[i];
        ((float4*)Wrs)[i] = ((const float4*)Wr)[i];
    }
    for (int i = tid; i < 32 * D / 4; i += 256) {
        ((float4*)x_s)[i] = ((const float4*)&x[(size_t)base * D])[i];
    }
    __syncthreads();

    int wv = tid >> 6;
    int f = tid & 63;
    float bf = bias[f];
    int m0 = wv * 8;                      // this wave's 8 local nodes

    float ya[8], za[8];
#pragma unroll
    for (int m = 0; m < 8; ++m) { ya[m] = 0.0f; za[m] = bf; }

#pragma unroll 4
    for (int k4 = 0; k4 < 16; ++k4) {
        int k = k4 * 4;
        // 8 per-lane b32 LDS reads (bank = f%32: 2-way alias, free)
        float w0 = Ws[(k + 0) * D + f], w1 = Ws[(k + 1) * D + f];
        float w2 = Ws[(k + 2) * D + f], w3 = Ws[(k + 3) * D + f];
        float u0 = Wrs[(k + 0) * D + f], u1 = Wrs[(k + 1) * D + f];
        float u2 = Wrs[(k + 2) * D + f], u3 = Wrs[(k + 3) * D + f];
#pragma unroll
        for (int m = 0; m < 8; ++m) {
            float4 xx = *(const float4*)&x_s[m0 + m][k];   // wave-uniform b128 broadcast
            ya[m] += xx.x * w0 + xx.y * w1 + xx.z * w2 + xx.w * w3;
            za[m] += xx.x * u0 + xx.y * u1 + xx.z * u2 + xx.w * u3;
        }
    }

#pragma unroll
    for (int m = 0; m < 8; ++m) {
        int r = base + m0 + m;
        float yn = __shfl_xor(ya[m], 1, 64);
        if ((f & 1) == 0) {
            __hip_bfloat16 lo = __float2bfloat16(ya[m]);   // RNE
            __hip_bfloat16 hi = __float2bfloat16(yn);
            unsigned int lo_u = *(const unsigned short*)&lo;
            unsigned int hi_u = *(const unsigned short*)&hi;
            y_packed[((size_t)r * D + f) >> 1] = lo_u | (hi_u << 16);
        }
        out[(size_t)r * D + f] = za[m];
    }
}

// ==================== pure gather-mean-add (unchanged) =======================
__device__ __forceinline__ float bf2f(unsigned short u) {
    union { unsigned int i; float f; } v;
    v.i = ((unsigned int)u) << 16;
    return v.f;
}

__launch_bounds__(256, 8)
__global__ void gather_kernel(const unsigned short* __restrict__ yu,
                              const int* __restrict__ cursor_end,
                              const int* __restrict__ deg,
                              const int* __restrict__ col_sorted,
                              float* __restrict__ out) {
    int wv = threadIdx.x >> 6;
    int lane = threadIdx.x & 63;
    int s = lane >> 4;
    int q = lane & 15;
    int node0 = (blockIdx.x * 4 + wv) * 4;   // 100000 = 6250*16

    int4 nv = *(const int4*)&deg[node0];        // degrees (16B aligned)
    int4 ev = *(const int4*)&cursor_end[node0]; // end offsets

    int st0 = ev.x - nv.x, st1 = ev.y - nv.y, st2 = ev.z - nv.z, st3 = ev.w - nv.w;

    int i0 = 0, i1 = 0, i2 = 0, i3 = 0;
    if (lane < nv.x) i0 = col_sorted[st0 + lane];
    if (lane < nv.y) i1 = col_sorted[st1 + lane];
    if (lane < nv.z) i2 = col_sorted[st2 + lane];
    if (lane < nv.w) i3 = col_sorted[st3 + lane];

    float4 a0 = make_float4(0.f, 0.f, 0.f, 0.f);
    float4 a1 = a0, a2 = a0, a3 = a0;

    // pair (0,1)
    {
        int m = nv.x > nv.y ? nv.x : nv.y;
        for (int j = 0; j < m; j += 4) {
            int jj = j + s;
            int c0 = __shfl(i0, jj, 64);
            int c1 = __shfl(i1, jj, 64);
            if (jj < nv.x) {
                ushort4 v = *(const ushort4*)&yu[(size_t)c0 * D + q * 4];
                a0.x += bf2f(v.x); a0.y += bf2f(v.y); a0.z += bf2f(v.z); a0.w += bf2f(v.w);
            }
            if (jj < nv.y) {
                ushort4 v = *(const ushort4*)&yu[(size_t)c1 * D + q * 4];
                a1.x += bf2f(v.x); a1.y += bf2f(v.y); a1.z += bf2f(v.z); a1.w += bf2f(v.w);
            }
        }
    }
    // pair (2,3)
    {
        int m = nv.z > nv.w ? nv.z : nv.w;
        for (int j = 0; j < m; j += 4) {
            int jj = j + s;
            int c2 = __shfl(i2, jj, 64);
            int c3 = __shfl(i3, jj, 64);
            if (jj < nv.z) {
                ushort4 v = *(const ushort4*)&yu[(size_t)c2 * D + q * 4];
                a2.x += bf2f(v.x); a2.y += bf2f(v.y); a2.z += bf2f(v.z); a2.w += bf2f(v.w);
            }
            if (jj < nv.w) {
                ushort4 v = *(const ushort4*)&yu[(size_t)c3 * D + q * 4];
                a3.x += bf2f(v.x); a3.y += bf2f(v.y); a3.z += bf2f(v.z); a3.w += bf2f(v.w);
            }
        }
    }

    // butterfly across s (bits 4,5)
#define BFLY(a) \
    a.x += __shfl_xor(a.x, 16, 64); a.y += __shfl_xor(a.y, 16, 64); \
    a.z += __shfl_xor(a.z, 16, 64); a.w += __shfl_xor(a.w, 16, 64); \
    a.x += __shfl_xor(a.x, 32, 64); a.y += __shfl_xor(a.y, 32, 64); \
    a.z += __shfl_xor(a.z, 32, 64); a.w += __shfl_xor(a.w, 32, 64);
    BFLY(a0) BFLY(a1) BFLY(a2) BFLY(a3)
#undef BFLY

    float inv0 = 1.0f / (float)(nv.x > 1 ? nv.x : 1);
    float inv1 = 1.0f / (float)(nv.y > 1 ? nv.y : 1);
    float inv2 = 1.0f / (float)(nv.z > 1 ? nv.z : 1);
    float inv3 = 1.0f / (float)(nv.w > 1 ? nv.w : 1);

    // lane (s,q) finalizes node node0+s, feature quad q: 1KB coalesced RMW
    float4 rr = (s == 0) ? a0 : (s == 1) ? a1 : (s == 2) ? a2 : a3;
    float invs = (s == 0) ? inv0 : (s == 1) ? inv1 : (s == 2) ? inv2 : inv3;
    size_t off = (size_t)(node0 + s) * D + q * 4;
    float4 z = *(const float4*)&out[off];
    z.x += rr.x * invs; z.y += rr.y * invs; z.z += rr.z * invs; z.w += rr.w * invs;
    *(float4*)&out[off] = z;
}

// ==================== round-5 fused aggregate (mid-tier fallback) ============
__launch_bounds__(512, 8)
__global__ void aggregate_kernel(const float* __restrict__ x,
                                 const int* __restrict__ cursor_end,
                                 const int* __restrict__ deg,
                                 const int* __restrict__ col_sorted,
                                 const float* __restrict__ W,
                                 const float* __restrict__ Wr,
                                 const float* __restrict__ bias,
                                 float* __restrict__ out) {
    __shared__ float Ws[D * D];
    __shared__ float Wrs[D * D];
    __shared__ float agg_s[8][D];
    __shared__ float x_s[8][D];

    for (int i = threadIdx.x; i < D * D / 4; i += 512) {
        ((float4*)Ws)[i]  = ((const float4*)W)[i];
        ((float4*)Wrs)[i] = ((const float4*)Wr)[i];
    }
    __syncthreads();

    int wv = threadIdx.x >> 6;
    int lane = threadIdx.x & 63;
    int s = lane >> 4;
    int q = lane & 15;
    float bf = bias[lane];

    int node0 = (blockIdx.x * 8 + wv) * 4;

#pragma unroll 1
    for (int nn = 0; nn < 4; ++nn) {
        int r = node0 + nn;
        int n = deg[r];
        int start = cursor_end[r] - n;

        float4 acc = make_float4(0.f, 0.f, 0.f, 0.f);
        for (int base = 0; base < n; base += 64) {
            int m = n - base; if (m > 64) m = 64;
            int idx = 0;
            if (lane < m) idx = col_sorted[start + base + lane];
            for (int j = 0; j < m; j += 4) {
                int jj = j + s;
                int c = __shfl(idx, jj, 64);
                if (jj < m) {
                    float4 v = *(const float4*)&x[(size_t)c * D + q * 4];
                    acc.x += v.x; acc.y += v.y; acc.z += v.z; acc.w += v.w;
                }
            }
        }
        acc.x += __shfl_xor(acc.x, 16, 64);
        acc.y += __shfl_xor(acc.y, 16, 64);
        acc.z += __shfl_xor(acc.z, 16, 64);
        acc.w += __shfl_xor(acc.w, 16, 64);
        acc.x += __shfl_xor(acc.x, 32, 64);
        acc.y += __shfl_xor(acc.y, 32, 64);
        acc.z += __shfl_xor(acc.z, 32, 64);
        acc.w += __shfl_xor(acc.w, 32, 64);

        float inv = 1.0f / (float)(n > 1 ? n : 1);
        if (lane < 16) {
            float4 a = make_float4(acc.x * inv, acc.y * inv, acc.z * inv, acc.w * inv);
            *(float4*)&agg_s[wv][q * 4] = a;
            *(float4*)&x_s[wv][q * 4] = *(const float4*)&x[(size_t)r * D + q * 4];
        }
        __builtin_amdgcn_wave_barrier();

        int f = lane;
        float o = bf;
        const float4* av = (const float4*)agg_s[wv];
        const float4* xv = (const float4*)x_s[wv];
#pragma unroll
        for (int k4 = 0; k4 < 16; ++k4) {
            float4 a = av[k4];
            float4 xx = xv[k4];
            int k = k4 * 4;
            o += a.x * Ws[(k + 0) * D + f] + xx.x * Wrs[(k + 0) * D + f];
            o += a.y * Ws[(k + 1) * D + f] + xx.y * Wrs[(k + 1) * D + f];
            o += a.z * Ws[(k + 2) * D + f] + xx.z * Wrs[(k + 2) * D + f];
            o += a.w * Ws[(k + 3) * D + f] + xx.w * Wrs[(k + 3) * D + f];
        }
        out[(size_t)r * D + f] = o;
        __builtin_amdgcn_wave_barrier();
    }
}

// ==================== atomic fallback path (needs 400 KB ws) ====================

__global__ void zero_kernel(float* __restrict__ summed, float* __restrict__ cnt) {
    int stride = gridDim.x * blockDim.x;
    int i = blockIdx.x * blockDim.x + threadIdx.x;
    const int total = N_NODES * D;
    for (int idx = i; idx < total; idx += stride) summed[idx] = 0.0f;
    for (int idx = i; idx < N_NODES; idx += stride) cnt[idx] = 0.0f;
}

__global__ void scatter_atomic_kernel(const float* __restrict__ x,
                                      const int* __restrict__ row,
                                      const int* __restrict__ col,
                                      float* __restrict__ summed,
                                      float* __restrict__ cnt) {
    long long gid = (long long)blockIdx.x * blockDim.x + threadIdx.x;
    const long long total = (long long)N_EDGES * D;
    if (gid >= total) return;
    int e = (int)(gid >> 6);
    int f = (int)(gid & 63);
    int r = row[e];
    int c = col[e];
    atomicAdd(&summed[r * D + f], x[c * D + f]);
    if (f == 0) atomicAdd(&cnt[r], 1.0f);
}

__global__ void finish_kernel(const float* __restrict__ x,
                              const float* __restrict__ W,
                              const float* __restrict__ Wr,
                              const float* __restrict__ bias,
                              const float* __restrict__ cnt,
                              float* __restrict__ out) {
    __shared__ float agg_s[4][D];
    __shared__ float x_s[4][D];
    int lrow = threadIdx.x >> 6;
    int f = threadIdx.x & 63;
    int r = blockIdx.x * 4 + lrow;

    float c = cnt[r];
    float inv = 1.0f / fmaxf(c, 1.0f);
    agg_s[lrow][f] = out[r * D + f] * inv;
    x_s[lrow][f] = x[r * D + f];
    __syncthreads();

    float acc = bias[f];
#pragma unroll 8
    for (int k = 0; k < D; ++k) {
        acc += agg_s[lrow][k] * W[k * D + f];
        acc += x_s[lrow][k] * Wr[k * D + f];
    }
    out[r * D + f] = acc;
}

// ==================== launch ====================

extern "C" void kernel_launch(void* const* d_in, const int* in_sizes, int n_in,
                              void* d_out, int out_size, void* d_ws, size_t ws_size,
                              hipStream_t stream) {
    const float* x    = (const float*)d_in[0];
    const int*   ei   = (const int*)d_in[1];   // [2, E]: row = ei, col = ei + E
    const float* W    = (const float*)d_in[2];
    const float* Wr   = (const float*)d_in[3];
    const float* bias = (const float*)d_in[4];
    float* out = (float*)d_out;

    const int* row = ei;
    const int* col = ei + N_EDGES;

    // ws layout: deg(N) | cursor(N) | bsum(2048B) | col_sorted(E) | y_bf16(N*D)
    const size_t csr_bytes = (size_t)2 * N_NODES * 4 + 2048 + (size_t)N_EDGES * 4;
    const size_t need_y    = csr_bytes + (size_t)N_NODES * D * 2;

    if (ws_size >= csr_bytes) {
        char* ws = (char*)d_ws;
        int* deg        = (int*)(ws);
        int* cursor     = (int*)(ws + (size_t)1 * N_NODES * 4);
        int* bsum       = (int*)(ws + (size_t)2 * N_NODES * 4);
        int* col_sorted = (int*)(ws + (size_t)2 * N_NODES * 4 + 2048);
        unsigned int* y_packed = (unsigned int*)(ws + csr_bytes);

        hipMemsetAsync(deg, 0, (size_t)N_NODES * 4, stream);
        hist_kernel<<<(N_EDGES / 4 + 255) / 256, 256, 0, stream>>>((const int4*)row, deg);
        scan_block_kernel<<<NB, 256, 0, stream>>>(deg, cursor, bsum);
        add_offsets_kernel<<<NB, 256, 0, stream>>>(cursor, bsum);
        scatter_build_kernel<<<(N_EDGES / 4 + 255) / 256, 256, 0, stream>>>(
            (const int4*)row, (const int4*)col, cursor, col_sorted);

        if (ws_size >= need_y) {
            precompute_kernel<<<N_NODES / 32, 256, 0, stream>>>(x, W, Wr, bias, y_packed, out);
            gather_kernel<<<N_NODES / 16, 256, 0, stream>>>(
                (const unsigned short*)y_packed, cursor, deg, col_sorted, out);
        } else {
            aggregate_kernel<<<N_NODES / 32, 512, 0, stream>>>(x, cursor, deg, col_sorted, W, Wr, bias, out);
        }
    } else {
        // atomic fallback (round-1 verified): out doubles as summed[]
        float* cnt = (float*)d_ws;   // N_NODES floats
        zero_kernel<<<4096, 256, 0, stream>>>(out, cnt);
        long long total = (long long)N_EDGES * D;
        int blocks = (int)((total + 255) / 256);
        scatter_atomic_kernel<<<blocks, 256, 0, stream>>>(x, row, col, out, cnt);
        finish_kernel<<<(N_NODES + 3) / 4, 256, 0, stream>>>(x, W, Wr, bias, cnt, out);
    }
}

// Round 9
// 217.586 us; speedup vs baseline: 5.7969x; 1.4129x over previous
//
#include <hip/hip_runtime.h>
#include <hip/hip_bf16.h>

#define N_NODES 100000
#define N_EDGES 1280000
#define D 64
#define NB ((N_NODES + 255) / 256)      // 391 (legacy scan blocks, tier-2)
#define NBKT 98                          // buckets of 1024 nodes
#define BIN_EPB 4096                     // edges per bin_kernel block

// ==================== tier-1 CSR build: bucketed, write-amp-free ============
// Round-8 lesson: per-edge random 4B stores into col_sorted cost 90 MB of
// writeback (18x amp) because each line is filled by edges from all XCDs.
// Fix: every pairs/col_sorted line is written by exactly ONE block.

// Count rows per bucket (bucket = row >> 10). bucket_cnt pre-zeroed.
__global__ void bin_count_kernel(const int* __restrict__ row,
                                 int* __restrict__ bucket_cnt) {
    __shared__ int cnt[128];
    if (threadIdx.x < 128) cnt[threadIdx.x] = 0;
    __syncthreads();
    int t = blockIdx.x * 256 + threadIdx.x;
    if (t < N_EDGES / 4) {
        int4 r = ((const int4*)row)[t];
        atomicAdd(&cnt[r.x >> 10], 1);
        atomicAdd(&cnt[r.y >> 10], 1);
        atomicAdd(&cnt[r.z >> 10], 1);
        atomicAdd(&cnt[r.w >> 10], 1);
    }
    __syncthreads();
    if (threadIdx.x < 128 && cnt[threadIdx.x] > 0)
        atomicAdd(&bucket_cnt[threadIdx.x], cnt[threadIdx.x]);
}

// Single block: exclusive-scan bucket counts -> bucket_base; cursor = base.
__global__ void scan_buckets_kernel(const int* __restrict__ bucket_cnt,
                                    int* __restrict__ bucket_base,
                                    int* __restrict__ bucket_cursor) {
    __shared__ int s[128];
    int tid = threadIdx.x;   // 128 threads
    int v = bucket_cnt[tid];
    s[tid] = v;
    __syncthreads();
    for (int d = 1; d < 128; d <<= 1) {
        int t = (tid >= d) ? s[tid - d] : 0;
        __syncthreads();
        s[tid] += t;
        __syncthreads();
    }
    int excl = s[tid] - v;
    bucket_base[tid] = excl;
    bucket_cursor[tid] = excl;
}

// Bin edges into per-bucket regions as packed u32 (r_local<<17 | col).
// 256 threads x 16 edges (registers). Per-(block,bucket) contiguous run
// reserved with ONE global atomicAdd -> runs (and their lines) are
// block-exclusive -> writeback amp ~1x.
__global__ void bin_kernel(const int* __restrict__ row,
                           const int* __restrict__ col,
                           int* __restrict__ bucket_cursor,
                           unsigned int* __restrict__ pairs) {
    __shared__ int cnt[128];
    __shared__ int gbase[128];
    __shared__ int lcur[128];

    int tid = threadIdx.x;
    if (tid < 128) { cnt[tid] = 0; lcur[tid] = 0; }
    __syncthreads();

    int rr[16], cc[16];
#pragma unroll
    for (int i = 0; i < 16; ++i) {
        int e = blockIdx.x * BIN_EPB + i * 256 + tid;   // coalesced per i
        if (e < N_EDGES) {
            rr[i] = row[e];
            cc[i] = col[e];
            atomicAdd(&cnt[rr[i] >> 10], 1);
        } else {
            rr[i] = -1;
        }
    }
    __syncthreads();
    if (tid < 128 && cnt[tid] > 0)
        gbase[tid] = atomicAdd(&bucket_cursor[tid], cnt[tid]);
    __syncthreads();

#pragma unroll
    for (int i = 0; i < 16; ++i) {
        if (rr[i] >= 0) {
            int b = rr[i] >> 10;
            int slot = atomicAdd(&lcur[b], 1);
            pairs[gbase[b] + slot] =
                ((unsigned int)(rr[i] & 1023) << 17) | (unsigned int)cc[i];
        }
    }
}

// One 1024-thread block per bucket: local histogram + scan + scatter.
// col_sorted writes land in the bucket's contiguous region, written only by
// this block -> L2-local, single writeback. Also emits deg / cursor_end.
__global__ void csr_build_kernel(const unsigned int* __restrict__ pairs,
                                 const int* __restrict__ bucket_base,
                                 const int* __restrict__ bucket_cursor,
                                 int* __restrict__ deg,
                                 int* __restrict__ cursor_end,
                                 int* __restrict__ col_sorted) {
    __shared__ int cnt_s[1024];
    __shared__ int lcur[1024];

    int b = blockIdx.x;
    int tid = threadIdx.x;
    int base = bucket_base[b];
    int m = bucket_cursor[b] - base;

    cnt_s[tid] = 0;
    __syncthreads();
    for (int i = tid; i < m; i += 1024) {
        unsigned int p = pairs[base + i];
        atomicAdd(&cnt_s[p >> 17], 1);
    }
    __syncthreads();

    int myc = cnt_s[tid];
    // inclusive scan over 1024
    for (int d = 1; d < 1024; d <<= 1) {
        int t = (tid >= d) ? cnt_s[tid - d] : 0;
        __syncthreads();
        cnt_s[tid] += t;
        __syncthreads();
    }
    int incl = cnt_s[tid];
    int excl = incl - myc;
    lcur[tid] = excl;

    int g = b * 1024 + tid;
    if (g < N_NODES) {
        deg[g] = myc;
        cursor_end[g] = base + incl;
    }
    __syncthreads();

    for (int i = tid; i < m; i += 1024) {
        unsigned int p = pairs[base + i];
        int r = (int)(p >> 17);
        int slot = atomicAdd(&lcur[r], 1);
        col_sorted[base + slot] = (int)(p & 0x1FFFFu);
    }
}

// ==================== dense precompute, register-blocked =====================
// y = x@W (bf16, pair-packed dword stores); out = x@Wr + bias (fp32).
// 256 threads = 4 waves; 8 nodes/wave; W/Wr/x-tile in LDS (40 KB).
// No launch_bounds (round-6 spill lesson).
__global__ void precompute_kernel(const float* __restrict__ x,
                                  const float* __restrict__ W,
                                  const float* __restrict__ Wr,
                                  const float* __restrict__ bias,
                                  unsigned int* __restrict__ y_packed,
                                  float* __restrict__ out) {
    __shared__ float Ws[D * D];
    __shared__ float Wrs[D * D];
    __shared__ float x_s[32][D];

    int tid = threadIdx.x;
    int base = blockIdx.x * 32;           // N_NODES % 32 == 0
    for (int i = tid; i < D * D / 4; i += 256) {
        ((float4*)Ws)[i]  = ((const float4*)W)[i];
        ((float4*)Wrs)[i] = ((const float4*)Wr)[i];
    }
    for (int i = tid; i < 32 * D / 4; i += 256) {
        ((float4*)x_s)[i] = ((const float4*)&x[(size_t)base * D])[i];
    }
    __syncthreads();

    int wv = tid >> 6;
    int f = tid & 63;
    float bf = bias[f];
    int m0 = wv * 8;

    float ya[8], za[8];
#pragma unroll
    for (int m = 0; m < 8; ++m) { ya[m] = 0.0f; za[m] = bf; }

#pragma unroll 4
    for (int k4 = 0; k4 < 16; ++k4) {
        int k = k4 * 4;
        float w0 = Ws[(k + 0) * D + f], w1 = Ws[(k + 1) * D + f];
        float w2 = Ws[(k + 2) * D + f], w3 = Ws[(k + 3) * D + f];
        float u0 = Wrs[(k + 0) * D + f], u1 = Wrs[(k + 1) * D + f];
        float u2 = Wrs[(k + 2) * D + f], u3 = Wrs[(k + 3) * D + f];
#pragma unroll
        for (int m = 0; m < 8; ++m) {
            float4 xx = *(const float4*)&x_s[m0 + m][k];   // wave-uniform b128
            ya[m] += xx.x * w0 + xx.y * w1 + xx.z * w2 + xx.w * w3;
            za[m] += xx.x * u0 + xx.y * u1 + xx.z * u2 + xx.w * u3;
        }
    }

#pragma unroll
    for (int m = 0; m < 8; ++m) {
        int r = base + m0 + m;
        float yn = __shfl_xor(ya[m], 1, 64);
        if ((f & 1) == 0) {
            __hip_bfloat16 lo = __float2bfloat16(ya[m]);   // RNE
            __hip_bfloat16 hi = __float2bfloat16(yn);
            unsigned int lo_u = *(const unsigned short*)&lo;
            unsigned int hi_u = *(const unsigned short*)&hi;
            y_packed[((size_t)r * D + f) >> 1] = lo_u | (hi_u << 16);
        }
        out[(size_t)r * D + f] = za[m];
    }
}

// ==================== pure gather-mean-add ====================
__device__ __forceinline__ float bf2f(unsigned short u) {
    union { unsigned int i; float f; } v;
    v.i = ((unsigned int)u) << 16;
    return v.f;
}

__launch_bounds__(256, 8)
__global__ void gather_kernel(const unsigned short* __restrict__ yu,
                              const int* __restrict__ cursor_end,
                              const int* __restrict__ deg,
                              const int* __restrict__ col_sorted,
                              float* __restrict__ out) {
    int wv = threadIdx.x >> 6;
    int lane = threadIdx.x & 63;
    int s = lane >> 4;
    int q = lane & 15;
    int node0 = (blockIdx.x * 4 + wv) * 4;   // 100000 = 6250*16

    int4 nv = *(const int4*)&deg[node0];
    int4 ev = *(const int4*)&cursor_end[node0];

    int st0 = ev.x - nv.x, st1 = ev.y - nv.y, st2 = ev.z - nv.z, st3 = ev.w - nv.w;

    int i0 = 0, i1 = 0, i2 = 0, i3 = 0;
    if (lane < nv.x) i0 = col_sorted[st0 + lane];
    if (lane < nv.y) i1 = col_sorted[st1 + lane];
    if (lane < nv.z) i2 = col_sorted[st2 + lane];
    if (lane < nv.w) i3 = col_sorted[st3 + lane];

    float4 a0 = make_float4(0.f, 0.f, 0.f, 0.f);
    float4 a1 = a0, a2 = a0, a3 = a0;

    {
        int m = nv.x > nv.y ? nv.x : nv.y;
        for (int j = 0; j < m; j += 4) {
            int jj = j + s;
            int c0 = __shfl(i0, jj, 64);
            int c1 = __shfl(i1, jj, 64);
            if (jj < nv.x) {
                ushort4 v = *(const ushort4*)&yu[(size_t)c0 * D + q * 4];
                a0.x += bf2f(v.x); a0.y += bf2f(v.y); a0.z += bf2f(v.z); a0.w += bf2f(v.w);
            }
            if (jj < nv.y) {
                ushort4 v = *(const ushort4*)&yu[(size_t)c1 * D + q * 4];
                a1.x += bf2f(v.x); a1.y += bf2f(v.y); a1.z += bf2f(v.z); a1.w += bf2f(v.w);
            }
        }
    }
    {
        int m = nv.z > nv.w ? nv.z : nv.w;
        for (int j = 0; j < m; j += 4) {
            int jj = j + s;
            int c2 = __shfl(i2, jj, 64);
            int c3 = __shfl(i3, jj, 64);
            if (jj < nv.z) {
                ushort4 v = *(const ushort4*)&yu[(size_t)c2 * D + q * 4];
                a2.x += bf2f(v.x); a2.y += bf2f(v.y); a2.z += bf2f(v.z); a2.w += bf2f(v.w);
            }
            if (jj < nv.w) {
                ushort4 v = *(const ushort4*)&yu[(size_t)c3 * D + q * 4];
                a3.x += bf2f(v.x); a3.y += bf2f(v.y); a3.z += bf2f(v.z); a3.w += bf2f(v.w);
            }
        }
    }

#define BFLY(a) \
    a.x += __shfl_xor(a.x, 16, 64); a.y += __shfl_xor(a.y, 16, 64); \
    a.z += __shfl_xor(a.z, 16, 64); a.w += __shfl_xor(a.w, 16, 64); \
    a.x += __shfl_xor(a.x, 32, 64); a.y += __shfl_xor(a.y, 32, 64); \
    a.z += __shfl_xor(a.z, 32, 64); a.w += __shfl_xor(a.w, 32, 64);
    BFLY(a0) BFLY(a1) BFLY(a2) BFLY(a3)
#undef BFLY

    float inv0 = 1.0f / (float)(nv.x > 1 ? nv.x : 1);
    float inv1 = 1.0f / (float)(nv.y > 1 ? nv.y : 1);
    float inv2 = 1.0f / (float)(nv.z > 1 ? nv.z : 1);
    float inv3 = 1.0f / (float)(nv.w > 1 ? nv.w : 1);

    float4 rr = (s == 0) ? a0 : (s == 1) ? a1 : (s == 2) ? a2 : a3;
    float invs = (s == 0) ? inv0 : (s == 1) ? inv1 : (s == 2) ? inv2 : inv3;
    size_t off = (size_t)(node0 + s) * D + q * 4;
    float4 z = *(const float4*)&out[off];
    z.x += rr.x * invs; z.y += rr.y * invs; z.z += rr.z * invs; z.w += rr.w * invs;
    *(float4*)&out[off] = z;
}

// ==================== tier-2: legacy CSR build + fused aggregate ============

__global__ void hist_kernel(const int4* __restrict__ row4, int* __restrict__ deg) {
    int t = blockIdx.x * blockDim.x + threadIdx.x;
    if (t < N_EDGES / 4) {
        int4 r = row4[t];
        atomicAdd(&deg[r.x], 1);
        atomicAdd(&deg[r.y], 1);
        atomicAdd(&deg[r.z], 1);
        atomicAdd(&deg[r.w], 1);
    }
}

__global__ void scan_block_kernel(const int* __restrict__ deg,
                                  int* __restrict__ cursor,
                                  int* __restrict__ bsum) {
    __shared__ int s[256];
    int tid = threadIdx.x;
    int gid = blockIdx.x * 256 + tid;
    int v = (gid < N_NODES) ? deg[gid] : 0;
    s[tid] = v;
    __syncthreads();
    for (int d = 1; d < 256; d <<= 1) {
        int t = (tid >= d) ? s[tid - d] : 0;
        __syncthreads();
        s[tid] += t;
        __syncthreads();
    }
    if (gid < N_NODES) cursor[gid] = s[tid] - v;
    if (tid == 255) bsum[blockIdx.x] = s[255];
}

__global__ void add_offsets_kernel(int* __restrict__ cursor,
                                   const int* __restrict__ bsum_raw) {
    __shared__ int red[256];
    int tid = threadIdx.x;
    int b = blockIdx.x;
    int sum = 0;
    for (int i = tid; i < b; i += 256) sum += bsum_raw[i];
    red[tid] = sum;
    __syncthreads();
    for (int off = 128; off > 0; off >>= 1) {
        if (tid < off) red[tid] += red[tid + off];
        __syncthreads();
    }
    int gid = b * 256 + tid;
    if (gid < N_NODES) cursor[gid] += red[0];
}

__global__ void scatter_build_kernel(const int4* __restrict__ row4,
                                     const int4* __restrict__ col4,
                                     int* __restrict__ cursor,
                                     int* __restrict__ col_sorted) {
    int t = blockIdx.x * blockDim.x + threadIdx.x;
    if (t < N_EDGES / 4) {
        int4 r = row4[t];
        int4 c = col4[t];
        col_sorted[atomicAdd(&cursor[r.x], 1)] = c.x;
        col_sorted[atomicAdd(&cursor[r.y], 1)] = c.y;
        col_sorted[atomicAdd(&cursor[r.z], 1)] = c.z;
        col_sorted[atomicAdd(&cursor[r.w], 1)] = c.w;
    }
}

__launch_bounds__(512, 8)
__global__ void aggregate_kernel(const float* __restrict__ x,
                                 const int* __restrict__ cursor_end,
                                 const int* __restrict__ deg,
                                 const int* __restrict__ col_sorted,
                                 const float* __restrict__ W,
                                 const float* __restrict__ Wr,
                                 const float* __restrict__ bias,
                                 float* __restrict__ out) {
    __shared__ float Ws[D * D];
    __shared__ float Wrs[D * D];
    __shared__ float agg_s[8][D];
    __shared__ float x_s[8][D];

    for (int i = threadIdx.x; i < D * D / 4; i += 512) {
        ((float4*)Ws)[i]  = ((const float4*)W)[i];
        ((float4*)Wrs)[i] = ((const float4*)Wr)[i];
    }
    __syncthreads();

    int wv = threadIdx.x >> 6;
    int lane = threadIdx.x & 63;
    int s = lane >> 4;
    int q = lane & 15;
    float bf = bias[lane];

    int node0 = (blockIdx.x * 8 + wv) * 4;

#pragma unroll 1
    for (int nn = 0; nn < 4; ++nn) {
        int r = node0 + nn;
        int n = deg[r];
        int start = cursor_end[r] - n;

        float4 acc = make_float4(0.f, 0.f, 0.f, 0.f);
        for (int base = 0; base < n; base += 64) {
            int m = n - base; if (m > 64) m = 64;
            int idx = 0;
            if (lane < m) idx = col_sorted[start + base + lane];
            for (int j = 0; j < m; j += 4) {
                int jj = j + s;
                int c = __shfl(idx, jj, 64);
                if (jj < m) {
                    float4 v = *(const float4*)&x[(size_t)c * D + q * 4];
                    acc.x += v.x; acc.y += v.y; acc.z += v.z; acc.w += v.w;
                }
            }
        }
        acc.x += __shfl_xor(acc.x, 16, 64);
        acc.y += __shfl_xor(acc.y, 16, 64);
        acc.z += __shfl_xor(acc.z, 16, 64);
        acc.w += __shfl_xor(acc.w, 16, 64);
        acc.x += __shfl_xor(acc.x, 32, 64);
        acc.y += __shfl_xor(acc.y, 32, 64);
        acc.z += __shfl_xor(acc.z, 32, 64);
        acc.w += __shfl_xor(acc.w, 32, 64);

        float inv = 1.0f / (float)(n > 1 ? n : 1);
        if (lane < 16) {
            float4 a = make_float4(acc.x * inv, acc.y * inv, acc.z * inv, acc.w * inv);
            *(float4*)&agg_s[wv][q * 4] = a;
            *(float4*)&x_s[wv][q * 4] = *(const float4*)&x[(size_t)r * D + q * 4];
        }
        __builtin_amdgcn_wave_barrier();

        int f = lane;
        float o = bf;
        const float4* av = (const float4*)agg_s[wv];
        const float4* xv = (const float4*)x_s[wv];
#pragma unroll
        for (int k4 = 0; k4 < 16; ++k4) {
            float4 a = av[k4];
            float4 xx = xv[k4];
            int k = k4 * 4;
            o += a.x * Ws[(k + 0) * D + f] + xx.x * Wrs[(k + 0) * D + f];
            o += a.y * Ws[(k + 1) * D + f] + xx.y * Wrs[(k + 1) * D + f];
            o += a.z * Ws[(k + 2) * D + f] + xx.z * Wrs[(k + 2) * D + f];
            o += a.w * Ws[(k + 3) * D + f] + xx.w * Wrs[(k + 3) * D + f];
        }
        out[(size_t)r * D + f] = o;
        __builtin_amdgcn_wave_barrier();
    }
}

// ==================== tier-3: atomic fallback (400 KB ws) ====================

__global__ void zero_kernel(float* __restrict__ summed, float* __restrict__ cnt) {
    int stride = gridDim.x * blockDim.x;
    int i = blockIdx.x * blockDim.x + threadIdx.x;
    const int total = N_NODES * D;
    for (int idx = i; idx < total; idx += stride) summed[idx] = 0.0f;
    for (int idx = i; idx < N_NODES; idx += stride) cnt[idx] = 0.0f;
}

__global__ void scatter_atomic_kernel(const float* __restrict__ x,
                                      const int* __restrict__ row,
                                      const int* __restrict__ col,
                                      float* __restrict__ summed,
                                      float* __restrict__ cnt) {
    long long gid = (long long)blockIdx.x * blockDim.x + threadIdx.x;
    const long long total = (long long)N_EDGES * D;
    if (gid >= total) return;
    int e = (int)(gid >> 6);
    int f = (int)(gid & 63);
    int r = row[e];
    int c = col[e];
    atomicAdd(&summed[r * D + f], x[c * D + f]);
    if (f == 0) atomicAdd(&cnt[r], 1.0f);
}

__global__ void finish_kernel(const float* __restrict__ x,
                              const float* __restrict__ W,
                              const float* __restrict__ Wr,
                              const float* __restrict__ bias,
                              const float* __restrict__ cnt,
                              float* __restrict__ out) {
    __shared__ float agg_s[4][D];
    __shared__ float x_s[4][D];
    int lrow = threadIdx.x >> 6;
    int f = threadIdx.x & 63;
    int r = blockIdx.x * 4 + lrow;

    float c = cnt[r];
    float inv = 1.0f / fmaxf(c, 1.0f);
    agg_s[lrow][f] = out[r * D + f] * inv;
    x_s[lrow][f] = x[r * D + f];
    __syncthreads();

    float acc = bias[f];
#pragma unroll 8
    for (int k = 0; k < D; ++k) {
        acc += agg_s[lrow][k] * W[k * D + f];
        acc += x_s[lrow][k] * Wr[k * D + f];
    }
    out[r * D + f] = acc;
}

// ==================== launch ====================

extern "C" void kernel_launch(void* const* d_in, const int* in_sizes, int n_in,
                              void* d_out, int out_size, void* d_ws, size_t ws_size,
                              hipStream_t stream) {
    const float* x    = (const float*)d_in[0];
    const int*   ei   = (const int*)d_in[1];   // [2, E]: row = ei, col = ei + E
    const float* W    = (const float*)d_in[2];
    const float* Wr   = (const float*)d_in[3];
    const float* bias = (const float*)d_in[4];
    float* out = (float*)d_out;

    const int* row = ei;
    const int* col = ei + N_EDGES;

    // tier-1 layout (pairs overlays y -- pairs dead before precompute runs):
    //   deg(400000) | cursor_end(400000) | bucket_base(512) | bucket_cursor(512)
    //   | col_sorted(E*4) | union{ pairs(E*4), y(N*D*2) }
    const size_t t1_deg   = 0;
    const size_t t1_cend  = 400000;
    const size_t t1_bbase = 800000;
    const size_t t1_bcur  = 800512;
    const size_t t1_csort = 801024;
    const size_t t1_pairs = t1_csort + (size_t)N_EDGES * 4;        // 5,921,024
    const size_t t1_need  = t1_pairs + (size_t)N_NODES * D * 2;    // 18,721,024

    const size_t csr_bytes = (size_t)2 * N_NODES * 4 + 2048 + (size_t)N_EDGES * 4;

    if (ws_size >= t1_need) {
        char* ws = (char*)d_ws;
        int* deg        = (int*)(ws + t1_deg);
        int* cursor_end = (int*)(ws + t1_cend);
        int* bbase      = (int*)(ws + t1_bbase);
        int* bcur       = (int*)(ws + t1_bcur);
        int* col_sorted = (int*)(ws + t1_csort);
        unsigned int* pairs    = (unsigned int*)(ws + t1_pairs);
        unsigned int* y_packed = (unsigned int*)(ws + t1_pairs);   // overlay

        hipMemsetAsync(bcur, 0, 512, stream);                      // counts first
        bin_count_kernel<<<(N_EDGES / 4 + 255) / 256, 256, 0, stream>>>(row, bcur);
        scan_buckets_kernel<<<1, 128, 0, stream>>>(bcur, bbase, bcur);
        // note: scan reads counts from bcur then overwrites bcur with bases —
        // safe because each thread reads its value before any write (barrier-
        // separated in-kernel); bbase keeps the pristine bases.
        bin_kernel<<<(N_EDGES + BIN_EPB - 1) / BIN_EPB, 256, 0, stream>>>(
            row, col, bcur, pairs);
        csr_build_kernel<<<NBKT, 1024, 0, stream>>>(
            pairs, bbase, bcur, deg, cursor_end, col_sorted);
        precompute_kernel<<<N_NODES / 32, 256, 0, stream>>>(x, W, Wr, bias, y_packed, out);
        gather_kernel<<<N_NODES / 16, 256, 0, stream>>>(
            (const unsigned short*)y_packed, cursor_end, deg, col_sorted, out);
    } else if (ws_size >= csr_bytes) {
        char* ws = (char*)d_ws;
        int* deg        = (int*)(ws);
        int* cursor     = (int*)(ws + (size_t)1 * N_NODES * 4);
        int* bsum       = (int*)(ws + (size_t)2 * N_NODES * 4);
        int* col_sorted = (int*)(ws + (size_t)2 * N_NODES * 4 + 2048);

        hipMemsetAsync(deg, 0, (size_t)N_NODES * 4, stream);
        hist_kernel<<<(N_EDGES / 4 + 255) / 256, 256, 0, stream>>>((const int4*)row, deg);
        scan_block_kernel<<<NB, 256, 0, stream>>>(deg, cursor, bsum);
        add_offsets_kernel<<<NB, 256, 0, stream>>>(cursor, bsum);
        scatter_build_kernel<<<(N_EDGES / 4 + 255) / 256, 256, 0, stream>>>(
            (const int4*)row, (const int4*)col, cursor, col_sorted);
        aggregate_kernel<<<N_NODES / 32, 512, 0, stream>>>(x, cursor, deg, col_sorted, W, Wr, bias, out);
    } else {
        float* cnt = (float*)d_ws;   // N_NODES floats
        zero_kernel<<<4096, 256, 0, stream>>>(out, cnt);
        long long total = (long long)N_EDGES * D;
        int blocks = (int)((total + 255) / 256);
        scatter_atomic_kernel<<<blocks, 256, 0, stream>>>(x, row, col, out, cnt);
        finish_kernel<<<(N_NODES + 3) / 4, 256, 0, stream>>>(x, W, Wr, bias, cnt, out);
    }
}

// Round 10
// 204.281 us; speedup vs baseline: 6.1744x; 1.0651x over previous
//
#include <hip/hip_runtime.h>
#include <hip/hip_bf16.h>

#define N_NODES 100000
#define N_EDGES 1280000
#define D 64
#define NB ((N_NODES + 255) / 256)      // 391 (legacy scan blocks, tier-2)
#define NBKT 98                          // buckets of 1024 nodes
#define BIN_EPB 4096                     // edges per bin_kernel block

using short8 = __attribute__((ext_vector_type(8))) short;
using f32x4  = __attribute__((ext_vector_type(4))) float;

__device__ __forceinline__ unsigned short f2bf(float f) {
    unsigned int u = __float_as_uint(f);
    unsigned int r = (u + 0x7FFFu + ((u >> 16) & 1u)) >> 16;   // RNE
    return (unsigned short)r;
}

// ==================== tier-1 CSR build: bucketed, write-amp-free ============
// Round-8 lesson: per-edge random 4B stores into col_sorted cost 90 MB of
// writeback (18x amp). Fix: every pairs/col_sorted line is written by ONE block.

__global__ void bin_count_kernel(const int* __restrict__ row,
                                 int* __restrict__ bucket_cnt) {
    __shared__ int cnt[128];
    if (threadIdx.x < 128) cnt[threadIdx.x] = 0;
    __syncthreads();
    int t = blockIdx.x * 256 + threadIdx.x;
    if (t < N_EDGES / 4) {
        int4 r = ((const int4*)row)[t];
        atomicAdd(&cnt[r.x >> 10], 1);
        atomicAdd(&cnt[r.y >> 10], 1);
        atomicAdd(&cnt[r.z >> 10], 1);
        atomicAdd(&cnt[r.w >> 10], 1);
    }
    __syncthreads();
    if (threadIdx.x < 128 && cnt[threadIdx.x] > 0)
        atomicAdd(&bucket_cnt[threadIdx.x], cnt[threadIdx.x]);
}

__global__ void scan_buckets_kernel(const int* __restrict__ bucket_cnt,
                                    int* __restrict__ bucket_base,
                                    int* __restrict__ bucket_cursor) {
    __shared__ int s[128];
    int tid = threadIdx.x;   // 128 threads
    int v = bucket_cnt[tid];
    s[tid] = v;
    __syncthreads();
    for (int d = 1; d < 128; d <<= 1) {
        int t = (tid >= d) ? s[tid - d] : 0;
        __syncthreads();
        s[tid] += t;
        __syncthreads();
    }
    int excl = s[tid] - v;
    bucket_base[tid] = excl;
    bucket_cursor[tid] = excl;
}

__global__ void bin_kernel(const int* __restrict__ row,
                           const int* __restrict__ col,
                           int* __restrict__ bucket_cursor,
                           unsigned int* __restrict__ pairs) {
    __shared__ int cnt[128];
    __shared__ int gbase[128];
    __shared__ int lcur[128];

    int tid = threadIdx.x;
    if (tid < 128) { cnt[tid] = 0; lcur[tid] = 0; }
    __syncthreads();

    int rr[16], cc[16];
#pragma unroll
    for (int i = 0; i < 16; ++i) {
        int e = blockIdx.x * BIN_EPB + i * 256 + tid;   // coalesced per i
        if (e < N_EDGES) {
            rr[i] = row[e];
            cc[i] = col[e];
            atomicAdd(&cnt[rr[i] >> 10], 1);
        } else {
            rr[i] = -1;
        }
    }
    __syncthreads();
    if (tid < 128 && cnt[tid] > 0)
        gbase[tid] = atomicAdd(&bucket_cursor[tid], cnt[tid]);
    __syncthreads();

#pragma unroll
    for (int i = 0; i < 16; ++i) {
        if (rr[i] >= 0) {
            int b = rr[i] >> 10;
            int slot = atomicAdd(&lcur[b], 1);
            pairs[gbase[b] + slot] =
                ((unsigned int)(rr[i] & 1023) << 17) | (unsigned int)cc[i];
        }
    }
}

__global__ void csr_build_kernel(const unsigned int* __restrict__ pairs,
                                 const int* __restrict__ bucket_base,
                                 const int* __restrict__ bucket_cursor,
                                 int* __restrict__ deg,
                                 int* __restrict__ cursor_end,
                                 int* __restrict__ col_sorted) {
    __shared__ int cnt_s[1024];
    __shared__ int lcur[1024];

    int b = blockIdx.x;
    int tid = threadIdx.x;
    int base = bucket_base[b];
    int m = bucket_cursor[b] - base;

    cnt_s[tid] = 0;
    __syncthreads();
    for (int i = tid; i < m; i += 1024) {
        unsigned int p = pairs[base + i];
        atomicAdd(&cnt_s[p >> 17], 1);
    }
    __syncthreads();

    int myc = cnt_s[tid];
    for (int d = 1; d < 1024; d <<= 1) {
        int t = (tid >= d) ? cnt_s[tid - d] : 0;
        __syncthreads();
        cnt_s[tid] += t;
        __syncthreads();
    }
    int incl = cnt_s[tid];
    int excl = incl - myc;
    lcur[tid] = excl;

    int g = b * 1024 + tid;
    if (g < N_NODES) {
        deg[g] = myc;
        cursor_end[g] = base + incl;
    }
    __syncthreads();

    for (int i = tid; i < m; i += 1024) {
        unsigned int p = pairs[base + i];
        int r = (int)(p >> 17);
        int slot = atomicAdd(&lcur[r], 1);
        col_sorted[base + slot] = (int)(p & 0x1FFFFu);
    }
}

// ==================== dense precompute on MFMA ==============================
// y = x@W (bf16, pair-packed dword stores); out = x@Wr + bias (fp32 store,
// bf16 MFMA compute). One wave per 16 nodes; 4 waves/block; grid 1563.
// W/Wr converted once per block into LDS in B-fragment order so each
// fragment is a single aligned ds_read_b128.
// Layouts (m89/m120-verified): A[m=lane&15][k=(lane>>4)*8+j];
// B[k=(lane>>4)*8+j][n=lane&15]; C/D col=lane&15, row=(lane>>4)*4+reg.
__global__ void precompute_kernel(const float* __restrict__ x,
                                  const float* __restrict__ W,
                                  const float* __restrict__ Wr,
                                  const float* __restrict__ bias,
                                  unsigned int* __restrict__ y_packed,
                                  float* __restrict__ out) {
    __shared__ unsigned short Wl[8192];   // [mat][t][h][lane][j] bf16, 16 KB

    int tid = threadIdx.x;
    for (int idx = tid; idx < 8192; idx += 256) {
        int j    = idx & 7;
        int lane = (idx >> 3) & 63;
        int h    = (idx >> 9) & 1;
        int t    = (idx >> 10) & 3;
        int mat  = idx >> 12;
        int k = h * 32 + ((lane >> 4) << 3) + j;
        int n = t * 16 + (lane & 15);
        const float* src = mat ? Wr : W;
        Wl[idx] = f2bf(src[k * D + n]);
    }
    __syncthreads();

    int wv = tid >> 6;
    int lane = tid & 63;
    int g = blockIdx.x * 4 + wv;          // 16-node group id, 6250 groups
    if (g >= N_NODES / 16) return;

    int quad = lane >> 4;
    int n16 = lane & 15;
    int m_node = g * 16 + n16;            // this lane's A-operand row

    // A fragments: k = h*32 + quad*8 + j  -> two coalesced float4 loads/half
    short8 A[2];
#pragma unroll
    for (int h = 0; h < 2; ++h) {
        const float* xr = x + (size_t)m_node * D + h * 32 + quad * 8;
        float4 xa = *(const float4*)xr;
        float4 xb = *(const float4*)(xr + 4);
        short8 a;
        a[0] = (short)f2bf(xa.x); a[1] = (short)f2bf(xa.y);
        a[2] = (short)f2bf(xa.z); a[3] = (short)f2bf(xa.w);
        a[4] = (short)f2bf(xb.x); a[5] = (short)f2bf(xb.y);
        a[6] = (short)f2bf(xb.z); a[7] = (short)f2bf(xb.w);
        A[h] = a;
    }

    int row0 = g * 16 + quad * 4;         // C/D rows this lane writes

#pragma unroll
    for (int t = 0; t < 4; ++t) {
        short8 By0 = *(const short8*)&Wl[(((0 * 4 + t) * 2 + 0) * 64 + lane) * 8];
        short8 By1 = *(const short8*)&Wl[(((0 * 4 + t) * 2 + 1) * 64 + lane) * 8];
        short8 Bz0 = *(const short8*)&Wl[(((1 * 4 + t) * 2 + 0) * 64 + lane) * 8];
        short8 Bz1 = *(const short8*)&Wl[(((1 * 4 + t) * 2 + 1) * 64 + lane) * 8];

        f32x4 accY = {0.f, 0.f, 0.f, 0.f};
        accY = __builtin_amdgcn_mfma_f32_16x16x32_bf16(A[0], By0, accY, 0, 0, 0);
        accY = __builtin_amdgcn_mfma_f32_16x16x32_bf16(A[1], By1, accY, 0, 0, 0);
        f32x4 accZ = {0.f, 0.f, 0.f, 0.f};
        accZ = __builtin_amdgcn_mfma_f32_16x16x32_bf16(A[0], Bz0, accZ, 0, 0, 0);
        accZ = __builtin_amdgcn_mfma_f32_16x16x32_bf16(A[1], Bz1, accZ, 0, 0, 0);

        float bv = bias[t * 16 + n16];
#pragma unroll
        for (int r = 0; r < 4; ++r) {
            out[(size_t)(row0 + r) * D + t * 16 + n16] = accZ[r] + bv;
            unsigned int me = f2bf(accY[r]);
            unsigned int nb = (unsigned int)__shfl_xor((int)me, 1, 64) & 0xFFFFu;
            if ((lane & 1) == 0)
                y_packed[((size_t)(row0 + r) * D + t * 16 + n16) >> 1] = me | (nb << 16);
        }
    }
}

// ==================== pure gather-mean-add ====================
__device__ __forceinline__ float bf2f(unsigned short u) {
    union { unsigned int i; float f; } v;
    v.i = ((unsigned int)u) << 16;
    return v.f;
}

__launch_bounds__(256, 8)
__global__ void gather_kernel(const unsigned short* __restrict__ yu,
                              const int* __restrict__ cursor_end,
                              const int* __restrict__ deg,
                              const int* __restrict__ col_sorted,
                              float* __restrict__ out) {
    int wv = threadIdx.x >> 6;
    int lane = threadIdx.x & 63;
    int s = lane >> 4;
    int q = lane & 15;
    int node0 = (blockIdx.x * 4 + wv) * 4;   // 100000 = 6250*16

    int4 nv = *(const int4*)&deg[node0];
    int4 ev = *(const int4*)&cursor_end[node0];

    int st0 = ev.x - nv.x, st1 = ev.y - nv.y, st2 = ev.z - nv.z, st3 = ev.w - nv.w;

    int i0 = 0, i1 = 0, i2 = 0, i3 = 0;
    if (lane < nv.x) i0 = col_sorted[st0 + lane];
    if (lane < nv.y) i1 = col_sorted[st1 + lane];
    if (lane < nv.z) i2 = col_sorted[st2 + lane];
    if (lane < nv.w) i3 = col_sorted[st3 + lane];

    float4 a0 = make_float4(0.f, 0.f, 0.f, 0.f);
    float4 a1 = a0, a2 = a0, a3 = a0;

    {
        int m = nv.x > nv.y ? nv.x : nv.y;
        for (int j = 0; j < m; j += 4) {
            int jj = j + s;
            int c0 = __shfl(i0, jj, 64);
            int c1 = __shfl(i1, jj, 64);
            if (jj < nv.x) {
                ushort4 v = *(const ushort4*)&yu[(size_t)c0 * D + q * 4];
                a0.x += bf2f(v.x); a0.y += bf2f(v.y); a0.z += bf2f(v.z); a0.w += bf2f(v.w);
            }
            if (jj < nv.y) {
                ushort4 v = *(const ushort4*)&yu[(size_t)c1 * D + q * 4];
                a1.x += bf2f(v.x); a1.y += bf2f(v.y); a1.z += bf2f(v.z); a1.w += bf2f(v.w);
            }
        }
    }
    {
        int m = nv.z > nv.w ? nv.z : nv.w;
        for (int j = 0; j < m; j += 4) {
            int jj = j + s;
            int c2 = __shfl(i2, jj, 64);
            int c3 = __shfl(i3, jj, 64);
            if (jj < nv.z) {
                ushort4 v = *(const ushort4*)&yu[(size_t)c2 * D + q * 4];
                a2.x += bf2f(v.x); a2.y += bf2f(v.y); a2.z += bf2f(v.z); a2.w += bf2f(v.w);
            }
            if (jj < nv.w) {
                ushort4 v = *(const ushort4*)&yu[(size_t)c3 * D + q * 4];
                a3.x += bf2f(v.x); a3.y += bf2f(v.y); a3.z += bf2f(v.z); a3.w += bf2f(v.w);
            }
        }
    }

#define BFLY(a) \
    a.x += __shfl_xor(a.x, 16, 64); a.y += __shfl_xor(a.y, 16, 64); \
    a.z += __shfl_xor(a.z, 16, 64); a.w += __shfl_xor(a.w, 16, 64); \
    a.x += __shfl_xor(a.x, 32, 64); a.y += __shfl_xor(a.y, 32, 64); \
    a.z += __shfl_xor(a.z, 32, 64); a.w += __shfl_xor(a.w, 32, 64);
    BFLY(a0) BFLY(a1) BFLY(a2) BFLY(a3)
#undef BFLY

    float inv0 = 1.0f / (float)(nv.x > 1 ? nv.x : 1);
    float inv1 = 1.0f / (float)(nv.y > 1 ? nv.y : 1);
    float inv2 = 1.0f / (float)(nv.z > 1 ? nv.z : 1);
    float inv3 = 1.0f / (float)(nv.w > 1 ? nv.w : 1);

    float4 rr = (s == 0) ? a0 : (s == 1) ? a1 : (s == 2) ? a2 : a3;
    float invs = (s == 0) ? inv0 : (s == 1) ? inv1 : (s == 2) ? inv2 : inv3;
    size_t off = (size_t)(node0 + s) * D + q * 4;
    float4 z = *(const float4*)&out[off];
    z.x += rr.x * invs; z.y += rr.y * invs; z.z += rr.z * invs; z.w += rr.w * invs;
    *(float4*)&out[off] = z;
}

// ==================== tier-2: legacy CSR build + fused aggregate ============

__global__ void hist_kernel(const int4* __restrict__ row4, int* __restrict__ deg) {
    int t = blockIdx.x * blockDim.x + threadIdx.x;
    if (t < N_EDGES / 4) {
        int4 r = row4[t];
        atomicAdd(&deg[r.x], 1);
        atomicAdd(&deg[r.y], 1);
        atomicAdd(&deg[r.z], 1);
        atomicAdd(&deg[r.w], 1);
    }
}

__global__ void scan_block_kernel(const int* __restrict__ deg,
                                  int* __restrict__ cursor,
                                  int* __restrict__ bsum) {
    __shared__ int s[256];
    int tid = threadIdx.x;
    int gid = blockIdx.x * 256 + tid;
    int v = (gid < N_NODES) ? deg[gid] : 0;
    s[tid] = v;
    __syncthreads();
    for (int d = 1; d < 256; d <<= 1) {
        int t = (tid >= d) ? s[tid - d] : 0;
        __syncthreads();
        s[tid] += t;
        __syncthreads();
    }
    if (gid < N_NODES) cursor[gid] = s[tid] - v;
    if (tid == 255) bsum[blockIdx.x] = s[255];
}

__global__ void add_offsets_kernel(int* __restrict__ cursor,
                                   const int* __restrict__ bsum_raw) {
    __shared__ int red[256];
    int tid = threadIdx.x;
    int b = blockIdx.x;
    int sum = 0;
    for (int i = tid; i < b; i += 256) sum += bsum_raw[i];
    red[tid] = sum;
    __syncthreads();
    for (int off = 128; off > 0; off >>= 1) {
        if (tid < off) red[tid] += red[tid + off];
        __syncthreads();
    }
    int gid = b * 256 + tid;
    if (gid < N_NODES) cursor[gid] += red[0];
}

__global__ void scatter_build_kernel(const int4* __restrict__ row4,
                                     const int4* __restrict__ col4,
                                     int* __restrict__ cursor,
                                     int* __restrict__ col_sorted) {
    int t = blockIdx.x * blockDim.x + threadIdx.x;
    if (t < N_EDGES / 4) {
        int4 r = row4[t];
        int4 c = col4[t];
        col_sorted[atomicAdd(&cursor[r.x], 1)] = c.x;
        col_sorted[atomicAdd(&cursor[r.y], 1)] = c.y;
        col_sorted[atomicAdd(&cursor[r.z], 1)] = c.z;
        col_sorted[atomicAdd(&cursor[r.w], 1)] = c.w;
    }
}

__launch_bounds__(512, 8)
__global__ void aggregate_kernel(const float* __restrict__ x,
                                 const int* __restrict__ cursor_end,
                                 const int* __restrict__ deg,
                                 const int* __restrict__ col_sorted,
                                 const float* __restrict__ W,
                                 const float* __restrict__ Wr,
                                 const float* __restrict__ bias,
                                 float* __restrict__ out) {
    __shared__ float Ws[D * D];
    __shared__ float Wrs[D * D];
    __shared__ float agg_s[8][D];
    __shared__ float x_s[8][D];

    for (int i = threadIdx.x; i < D * D / 4; i += 512) {
        ((float4*)Ws)[i]  = ((const float4*)W)[i];
        ((float4*)Wrs)[i] = ((const float4*)Wr)[i];
    }
    __syncthreads();

    int wv = threadIdx.x >> 6;
    int lane = threadIdx.x & 63;
    int s = lane >> 4;
    int q = lane & 15;
    float bf = bias[lane];

    int node0 = (blockIdx.x * 8 + wv) * 4;

#pragma unroll 1
    for (int nn = 0; nn < 4; ++nn) {
        int r = node0 + nn;
        int n = deg[r];
        int start = cursor_end[r] - n;

        float4 acc = make_float4(0.f, 0.f, 0.f, 0.f);
        for (int base = 0; base < n; base += 64) {
            int m = n - base; if (m > 64) m = 64;
            int idx = 0;
            if (lane < m) idx = col_sorted[start + base + lane];
            for (int j = 0; j < m; j += 4) {
                int jj = j + s;
                int c = __shfl(idx, jj, 64);
                if (jj < m) {
                    float4 v = *(const float4*)&x[(size_t)c * D + q * 4];
                    acc.x += v.x; acc.y += v.y; acc.z += v.z; acc.w += v.w;
                }
            }
        }
        acc.x += __shfl_xor(acc.x, 16, 64);
        acc.y += __shfl_xor(acc.y, 16, 64);
        acc.z += __shfl_xor(acc.z, 16, 64);
        acc.w += __shfl_xor(acc.w, 16, 64);
        acc.x += __shfl_xor(acc.x, 32, 64);
        acc.y += __shfl_xor(acc.y, 32, 64);
        acc.z += __shfl_xor(acc.z, 32, 64);
        acc.w += __shfl_xor(acc.w, 32, 64);

        float inv = 1.0f / (float)(n > 1 ? n : 1);
        if (lane < 16) {
            float4 a = make_float4(acc.x * inv, acc.y * inv, acc.z * inv, acc.w * inv);
            *(float4*)&agg_s[wv][q * 4] = a;
            *(float4*)&x_s[wv][q * 4] = *(const float4*)&x[(size_t)r * D + q * 4];
        }
        __builtin_amdgcn_wave_barrier();

        int f = lane;
        float o = bf;
        const float4* av = (const float4*)agg_s[wv];
        const float4* xv = (const float4*)x_s[wv];
#pragma unroll
        for (int k4 = 0; k4 < 16; ++k4) {
            float4 a = av[k4];
            float4 xx = xv[k4];
            int k = k4 * 4;
            o += a.x * Ws[(k + 0) * D + f] + xx.x * Wrs[(k + 0) * D + f];
            o += a.y * Ws[(k + 1) * D + f] + xx.y * Wrs[(k + 1) * D + f];
            o += a.z * Ws[(k + 2) * D + f] + xx.z * Wrs[(k + 2) * D + f];
            o += a.w * Ws[(k + 3) * D + f] + xx.w * Wrs[(k + 3) * D + f];
        }
        out[(size_t)r * D + f] = o;
        __builtin_amdgcn_wave_barrier();
    }
}

// ==================== tier-3: atomic fallback (400 KB ws) ====================

__global__ void zero_kernel(float* __restrict__ summed, float* __restrict__ cnt) {
    int stride = gridDim.x * blockDim.x;
    int i = blockIdx.x * blockDim.x + threadIdx.x;
    const int total = N_NODES * D;
    for (int idx = i; idx < total; idx += stride) summed[idx] = 0.0f;
    for (int idx = i; idx < N_NODES; idx += stride) cnt[idx] = 0.0f;
}

__global__ void scatter_atomic_kernel(const float* __restrict__ x,
                                      const int* __restrict__ row,
                                      const int* __restrict__ col,
                                      float* __restrict__ summed,
                                      float* __restrict__ cnt) {
    long long gid = (long long)blockIdx.x * blockDim.x + threadIdx.x;
    const long long total = (long long)N_EDGES * D;
    if (gid >= total) return;
    int e = (int)(gid >> 6);
    int f = (int)(gid & 63);
    int r = row[e];
    int c = col[e];
    atomicAdd(&summed[r * D + f], x[c * D + f]);
    if (f == 0) atomicAdd(&cnt[r], 1.0f);
}

__global__ void finish_kernel(const float* __restrict__ x,
                              const float* __restrict__ W,
                              const float* __restrict__ Wr,
                              const float* __restrict__ bias,
                              const float* __restrict__ cnt,
                              float* __restrict__ out) {
    __shared__ float agg_s[4][D];
    __shared__ float x_s[4][D];
    int lrow = threadIdx.x >> 6;
    int f = threadIdx.x & 63;
    int r = blockIdx.x * 4 + lrow;

    float c = cnt[r];
    float inv = 1.0f / fmaxf(c, 1.0f);
    agg_s[lrow][f] = out[r * D + f] * inv;
    x_s[lrow][f] = x[r * D + f];
    __syncthreads();

    float acc = bias[f];
#pragma unroll 8
    for (int k = 0; k < D; ++k) {
        acc += agg_s[lrow][k] * W[k * D + f];
        acc += x_s[lrow][k] * Wr[k * D + f];
    }
    out[r * D + f] = acc;
}

// ==================== launch ====================

extern "C" void kernel_launch(void* const* d_in, const int* in_sizes, int n_in,
                              void* d_out, int out_size, void* d_ws, size_t ws_size,
                              hipStream_t stream) {
    const float* x    = (const float*)d_in[0];
    const int*   ei   = (const int*)d_in[1];   // [2, E]: row = ei, col = ei + E
    const float* W    = (const float*)d_in[2];
    const float* Wr   = (const float*)d_in[3];
    const float* bias = (const float*)d_in[4];
    float* out = (float*)d_out;

    const int* row = ei;
    const int* col = ei + N_EDGES;

    // tier-1 layout (pairs overlays y -- pairs dead before precompute runs):
    //   deg(400000) | cursor_end(400000) | bucket_base(512) | bucket_cursor(512)
    //   | col_sorted(E*4) | union{ pairs(E*4), y(N*D*2) }
    const size_t t1_deg   = 0;
    const size_t t1_cend  = 400000;
    const size_t t1_bbase = 800000;
    const size_t t1_bcur  = 800512;
    const size_t t1_csort = 801024;
    const size_t t1_pairs = t1_csort + (size_t)N_EDGES * 4;        // 5,921,024
    const size_t t1_need  = t1_pairs + (size_t)N_NODES * D * 2;    // 18,721,024

    const size_t csr_bytes = (size_t)2 * N_NODES * 4 + 2048 + (size_t)N_EDGES * 4;

    if (ws_size >= t1_need) {
        char* ws = (char*)d_ws;
        int* deg        = (int*)(ws + t1_deg);
        int* cursor_end = (int*)(ws + t1_cend);
        int* bbase      = (int*)(ws + t1_bbase);
        int* bcur       = (int*)(ws + t1_bcur);
        int* col_sorted = (int*)(ws + t1_csort);
        unsigned int* pairs    = (unsigned int*)(ws + t1_pairs);
        unsigned int* y_packed = (unsigned int*)(ws + t1_pairs);   // overlay

        hipMemsetAsync(bcur, 0, 512, stream);
        bin_count_kernel<<<(N_EDGES / 4 + 255) / 256, 256, 0, stream>>>(row, bcur);
        scan_buckets_kernel<<<1, 128, 0, stream>>>(bcur, bbase, bcur);
        bin_kernel<<<(N_EDGES + BIN_EPB - 1) / BIN_EPB, 256, 0, stream>>>(
            row, col, bcur, pairs);
        csr_build_kernel<<<NBKT, 1024, 0, stream>>>(
            pairs, bbase, bcur, deg, cursor_end, col_sorted);
        precompute_kernel<<<(N_NODES / 16 + 3) / 4, 256, 0, stream>>>(
            x, W, Wr, bias, y_packed, out);
        gather_kernel<<<N_NODES / 16, 256, 0, stream>>>(
            (const unsigned short*)y_packed, cursor_end, deg, col_sorted, out);
    } else if (ws_size >= csr_bytes) {
        char* ws = (char*)d_ws;
        int* deg        = (int*)(ws);
        int* cursor     = (int*)(ws + (size_t)1 * N_NODES * 4);
        int* bsum       = (int*)(ws + (size_t)2 * N_NODES * 4);
        int* col_sorted = (int*)(ws + (size_t)2 * N_NODES * 4 + 2048);

        hipMemsetAsync(deg, 0, (size_t)N_NODES * 4, stream);
        hist_kernel<<<(N_EDGES / 4 + 255) / 256, 256, 0, stream>>>((const int4*)row, deg);
        scan_block_kernel<<<NB, 256, 0, stream>>>(deg, cursor, bsum);
        add_offsets_kernel<<<NB, 256, 0, stream>>>(cursor, bsum);
        scatter_build_kernel<<<(N_EDGES / 4 + 255) / 256, 256, 0, stream>>>(
            (const int4*)row, (const int4*)col, cursor, col_sorted);
        aggregate_kernel<<<N_NODES / 32, 512, 0, stream>>>(x, cursor, deg, col_sorted, W, Wr, bias, out);
    } else {
        float* cnt = (float*)d_ws;   // N_NODES floats
        zero_kernel<<<4096, 256, 0, stream>>>(out, cnt);
        long long total = (long long)N_EDGES * D;
        int blocks = (int)((total + 255) / 256);
        scatter_atomic_kernel<<<blocks, 256, 0, stream>>>(x, row, col, out, cnt);
        finish_kernel<<<(N_NODES + 3) / 4, 256, 0, stream>>>(x, W, Wr, bias, cnt, out);
    }
}